// Round 2
// baseline (2271.229 us; speedup 1.0000x reference)
//
#include <hip/hip_runtime.h>
#include <hip/hip_bf16.h>

#define D_MODEL 1024
#define N_HEAD 16
#define BSZ 2
#define QLEN 2048
#define LOCAL_SIZE 1000
#define QKV3 (3 * N_HEAD * 64) // 3072

typedef __hip_bfloat16 bf16;

static __device__ __forceinline__ float b2f(bf16 x) { return __bfloat162float(x); }

// mode: 0 = always bf16, 1 = always fp32, 2 = follow runtime flag (raw harness tensor)
static __device__ __forceinline__ int rmode(int m, int fl) { return (m == 2) ? fl : m; }
static __device__ __forceinline__ float ldm(const void* p, size_t i, int isf) {
    return isf ? ((const float*)p)[i] : b2f(((const bf16*)p)[i]);
}

// ---------------------------------------------------------------------------
// dtype detector: read first 256 halfwords of W_qkv as bf16. True-bf16 weights
// (~0.02 scale) -> all 256 small+finite. fp32 data -> ~half are mantissa
// garbage, only ~51% of those look small. Threshold 240 separates cleanly.
// flag: 0 = bf16 data, 1 = fp32 data.
// ---------------------------------------------------------------------------
__global__ void detect_kernel(const unsigned short* __restrict__ w, int* __restrict__ flag)
{
    if (threadIdx.x == 0 && blockIdx.x == 0) {
        int good = 0;
        for (int i = 0; i < 256; ++i) {
            unsigned int bits = ((unsigned int)w[i]) << 16;
            float v = __uint_as_float(bits);
            if (v == v && fabsf(v) < 8.0f) ++good; // finite & small
        }
        *flag = (good >= 240) ? 0 : 1;
    }
}

// ---------------------------------------------------------------------------
// Generic tiled GEMM: C[b][m][n] = sum_k A[m][k]*B[b][k][n] (+ add[b][m][n]) (+ bias[m])
// Operand dtypes resolved per-kernel from modes + runtime flag. fp32 accumulate.
// Tile 64x64, BK=16, 256 threads, 4x4 per thread.
// ---------------------------------------------------------------------------
__global__ __launch_bounds__(256)
void gemm_kernel(const void* __restrict__ A, int mA,
                 const void* __restrict__ B, int mB, size_t sB,
                 void* __restrict__ C, size_t sC, int c_is_bf16,
                 const void* __restrict__ addm, int mAdd, size_t sAdd,
                 const void* __restrict__ bias, int mBias,
                 int M, int N, int K, const int* __restrict__ flag)
{
    const int fl = *flag;
    const int fA = rmode(mA, fl), fB = rmode(mB, fl);
    const int fAdd = rmode(mAdd, fl), fBias = rmode(mBias, fl);

    const int b  = blockIdx.z;
    const int m0 = blockIdx.y * 64;
    const int n0 = blockIdx.x * 64;
    const int tid = threadIdx.x;
    const int tx = tid & 15, ty = tid >> 4;

    __shared__ float As[64][17]; // [m][k]
    __shared__ float Bs[16][65]; // [k][n]

    const size_t bOffB = (size_t)b * sB;
    float acc[4][4] = {};

    for (int k0 = 0; k0 < K; k0 += 16) {
        for (int idx = tid; idx < 64 * 16; idx += 256) {
            int m = idx >> 4, k = idx & 15;
            As[m][k] = ldm(A, (size_t)(m0 + m) * K + k0 + k, fA);
        }
        for (int idx = tid; idx < 16 * 64; idx += 256) {
            int k = idx >> 6, n = idx & 63;
            Bs[k][n] = ldm(B, bOffB + (size_t)(k0 + k) * N + n0 + n, fB);
        }
        __syncthreads();
#pragma unroll
        for (int k = 0; k < 16; ++k) {
            float av[4], bv[4];
#pragma unroll
            for (int i = 0; i < 4; ++i) av[i] = As[ty * 4 + i][k];
#pragma unroll
            for (int j = 0; j < 4; ++j) bv[j] = Bs[k][tx * 4 + j];
#pragma unroll
            for (int i = 0; i < 4; ++i)
#pragma unroll
                for (int j = 0; j < 4; ++j) acc[i][j] += av[i] * bv[j];
        }
        __syncthreads();
    }

#pragma unroll
    for (int i = 0; i < 4; ++i) {
        int m = m0 + ty * 4 + i;
#pragma unroll
        for (int j = 0; j < 4; ++j) {
            int n = n0 + tx * 4 + j;
            float v = acc[i][j];
            if (addm) v += ldm(addm, (size_t)b * sAdd + (size_t)m * N + n, fAdd);
            if (bias) v += ldm(bias, (size_t)m, fBias);
            if (c_is_bf16)
                ((bf16*)C)[(size_t)b * sC + (size_t)m * N + n] = __float2bfloat16(v);
            else
                ((float*)C)[(size_t)b * sC + (size_t)m * N + n] = v;
        }
    }
}

// ---------------------------------------------------------------------------
// Flash-style banded attention with fused rel-shift (workspace tensors bf16).
// BD[i,j] = dot(q+rrb, r_head_k[:, j-i+Q-1]); allowed band 0 <= i-j < LOCAL_SIZE.
// ---------------------------------------------------------------------------
__global__ __launch_bounds__(256)
void attn_kernel(const bf16* __restrict__ wh,  // [B][3072][Q]
                 const bf16* __restrict__ rhk, // [1024][Q]
                 const void* __restrict__ rwb, // [1024] raw
                 const void* __restrict__ rrb, // [1024] raw
                 bf16* __restrict__ av_out,    // [B][1024][Q]
                 const int* __restrict__ flag)
{
    const int fl = *flag;
    const int it = blockIdx.x;
    const int h  = blockIdx.y;
    const int b  = blockIdx.z;
    const int i0 = it * 64;
    const int tid = threadIdx.x;
    const int tx = tid & 15, ty = tid >> 4;

    __shared__ bf16 qrw[64][66]; // [d][ii]
    __shared__ bf16 qrr[64][66];
    __shared__ bf16 kt[64][66];  // [d][jj]
    __shared__ bf16 vt[64][66];  // [jj][d]
    __shared__ bf16 rt[64][128]; // [d][t], t in 0..126
    __shared__ bf16 Pt[64][66];  // [ii][jj]
    __shared__ float red[64][17];
    __shared__ float m_s[64], l_s[64], al_s[64];

    const size_t whB = (size_t)b * QKV3 * QLEN;

    for (int idx = tid; idx < 64 * 64; idx += 256) {
        int d = idx >> 6, ii = idx & 63;
        float q = b2f(wh[whB + (size_t)(h * 64 + d) * QLEN + i0 + ii]);
        qrw[d][ii] = __float2bfloat16(q + ldm(rwb, h * 64 + d, fl));
        qrr[d][ii] = __float2bfloat16(q + ldm(rrb, h * 64 + d, fl));
    }
    if (tid < 64) { m_s[tid] = -INFINITY; l_s[tid] = 0.f; }

    float O[4][4] = {}; // [ii = ty*4+a][d = tx*4+c]

    int lo = i0 - (LOCAL_SIZE - 1);
    if (lo < 0) lo = 0;
    const int jt_lo = lo >> 6;
    const int jt_hi = (i0 + 63) >> 6;
    const float scale = 0.125f;

    for (int jt = jt_lo; jt <= jt_hi; ++jt) {
        const int j0 = jt * 64;
        __syncthreads();
        for (int idx = tid; idx < 64 * 64; idx += 256) {
            int d = idx >> 6, jj = idx & 63;
            kt[d][jj] = wh[whB + (size_t)(1024 + h * 64 + d) * QLEN + j0 + jj];
            vt[jj][d] = wh[whB + (size_t)(2048 + h * 64 + d) * QLEN + j0 + jj];
        }
        const int pbase = j0 - i0 + QLEN - 1 - 63;
        for (int idx = tid; idx < 64 * 127; idx += 256) {
            int d = idx / 127, t = idx % 127;
            int p = pbase + t;
            bf16 v = __float2bfloat16(0.f);
            if (p >= 0 && p < QLEN) v = rhk[(size_t)(h * 64 + d) * QLEN + p];
            rt[d][t] = v;
        }
        __syncthreads();

        float s[4][4];
#pragma unroll
        for (int a = 0; a < 4; ++a)
#pragma unroll
            for (int c = 0; c < 4; ++c) s[a][c] = 0.f;
        const int tb = tx * 4 - ty * 4 + 63;
        for (int d = 0; d < 64; ++d) {
            float a1[4], a2[4], kv[4], rv[7];
#pragma unroll
            for (int a = 0; a < 4; ++a) {
                a1[a] = b2f(qrw[d][ty * 4 + a]);
                a2[a] = b2f(qrr[d][ty * 4 + a]);
            }
#pragma unroll
            for (int c = 0; c < 4; ++c) kv[c] = b2f(kt[d][tx * 4 + c]);
#pragma unroll
            for (int u = 0; u < 7; ++u) rv[u] = b2f(rt[d][tb - 3 + u]);
#pragma unroll
            for (int a = 0; a < 4; ++a)
#pragma unroll
                for (int c = 0; c < 4; ++c)
                    s[a][c] += a1[a] * kv[c] + a2[a] * rv[c - a + 3];
        }

#pragma unroll
        for (int a = 0; a < 4; ++a) {
            int i = i0 + ty * 4 + a;
            float mx = -INFINITY;
#pragma unroll
            for (int c = 0; c < 4; ++c) {
                int j = j0 + tx * 4 + c;
                int diff = i - j;
                if (diff < 0 || diff >= LOCAL_SIZE) s[a][c] = -INFINITY;
                else s[a][c] *= scale;
                mx = fmaxf(mx, s[a][c]);
            }
            red[ty * 4 + a][tx] = mx;
        }
        __syncthreads();
        if (tid < 64) {
            float mo = m_s[tid];
            float t = -INFINITY;
            for (int c = 0; c < 16; ++c) t = fmaxf(t, red[tid][c]);
            float mn = fmaxf(mo, t);
            m_s[tid] = mn;
            al_s[tid] = (mo == -INFINITY) ? 0.f : __expf(mo - mn);
        }
        __syncthreads();

#pragma unroll
        for (int a = 0; a < 4; ++a) {
            int ii = ty * 4 + a;
            float mn = m_s[ii];
            float sum = 0.f;
#pragma unroll
            for (int c = 0; c < 4; ++c) {
                float p = (mn == -INFINITY) ? 0.f : __expf(s[a][c] - mn);
                Pt[ii][tx * 4 + c] = __float2bfloat16(p);
                sum += p;
            }
            red[ii][tx] = sum;
        }
        __syncthreads();
        if (tid < 64) {
            float sum = 0.f;
            for (int c = 0; c < 16; ++c) sum += red[tid][c];
            l_s[tid] = l_s[tid] * al_s[tid] + sum;
        }

#pragma unroll
        for (int a = 0; a < 4; ++a) {
            float f = al_s[ty * 4 + a];
#pragma unroll
            for (int c = 0; c < 4; ++c) O[a][c] *= f;
        }
        for (int jj = 0; jj < 64; ++jj) {
            float pv[4];
#pragma unroll
            for (int a = 0; a < 4; ++a) pv[a] = b2f(Pt[ty * 4 + a][jj]);
#pragma unroll
            for (int c = 0; c < 4; ++c) {
                float vv = b2f(vt[jj][tx * 4 + c]);
#pragma unroll
                for (int a = 0; a < 4; ++a) O[a][c] += pv[a] * vv;
            }
        }
    }
    __syncthreads();

#pragma unroll
    for (int a = 0; a < 4; ++a) {
        int ii = ty * 4 + a;
        float inv = 1.f / l_s[ii];
#pragma unroll
        for (int c = 0; c < 4; ++c) {
            int d = tx * 4 + c;
            av_out[(size_t)b * D_MODEL * QLEN + (size_t)(h * 64 + d) * QLEN + i0 + ii] =
                __float2bfloat16(O[a][c] * inv);
        }
    }
}

// ---------------------------------------------------------------------------
// LayerNorm over d_model per (b,q) column of fp32 y; output dtype follows flag.
// ---------------------------------------------------------------------------
__global__ __launch_bounds__(256)
void ln_kernel(const float* __restrict__ y, void* __restrict__ out,
               const int* __restrict__ flag)
{
    const int fl = *flag;
    const int b  = blockIdx.y;
    const int q0 = blockIdx.x * 64;
    const int t  = threadIdx.x;
    const int ql = t & 63;
    const int sl = t >> 6;
    const int q  = q0 + ql;

    const float* yb = y + (size_t)b * D_MODEL * QLEN + q;
    float s = 0.f, ss = 0.f;
    for (int o = sl * 256; o < sl * 256 + 256; ++o) {
        float v = yb[(size_t)o * QLEN];
        s += v; ss += v * v;
    }
    __shared__ float sred[4][64], ssred[4][64];
    __shared__ float mu_s[64], rs_s[64];
    sred[sl][ql] = s; ssred[sl][ql] = ss;
    __syncthreads();
    if (t < 64) {
        float S  = sred[0][t] + sred[1][t] + sred[2][t] + sred[3][t];
        float SS = ssred[0][t] + ssred[1][t] + ssred[2][t] + ssred[3][t];
        float mu  = S / D_MODEL;
        float var = SS / D_MODEL - mu * mu;
        mu_s[t] = mu;
        rs_s[t] = rsqrtf(var + 1e-5f);
    }
    __syncthreads();
    const float mu = mu_s[ql], rs = rs_s[ql];
    const size_t obase = (size_t)b * D_MODEL * QLEN + q;
    for (int o = sl * 256; o < sl * 256 + 256; ++o) {
        float v = (yb[(size_t)o * QLEN] - mu) * rs;
        size_t oi = obase + (size_t)o * QLEN;
        if (fl) ((float*)out)[oi] = v;
        else    ((bf16*)out)[oi] = __float2bfloat16(v);
    }
}

// ---------------------------------------------------------------------------
extern "C" void kernel_launch(void* const* d_in, const int* in_sizes, int n_in,
                              void* d_out, int out_size, void* d_ws, size_t ws_size,
                              hipStream_t stream)
{
    const void* z1ss = d_in[0]; // [B][1024][Q] raw
    const void* pos  = d_in[1]; // [1][1024][Q] raw
    const void* u1ss = d_in[2]; // [B][3072][Q] raw
    const void* Wqkv = d_in[3]; // [3072][1024] raw
    const void* Wr   = d_in[4]; // [1024][1024] raw
    const void* rwb  = d_in[5]; // [1024] raw
    const void* rrb  = d_in[6]; // [1024] raw
    const void* Wo   = d_in[7]; // [1024][1024] raw
    const void* bo   = d_in[8]; // [1024] raw

    char* ws = (char*)d_ws;
    bf16* wh = (bf16*)ws;                              // 25.2 MB
    size_t off = (size_t)BSZ * QKV3 * QLEN * sizeof(bf16);
    bf16* rhk = (bf16*)(ws + off);                     // 4.2 MB
    off += (size_t)D_MODEL * QLEN * sizeof(bf16);
    bf16* avec = (bf16*)(ws + off);                    // 8.4 MB
    off += (size_t)BSZ * D_MODEL * QLEN * sizeof(bf16);
    int* flag = (int*)(ws + off);
    float* y = (float*)ws; // overlaps wh (dead after attention); 16.8 MB

    detect_kernel<<<1, 64, 0, stream>>>((const unsigned short*)Wqkv, flag);

    // 1. w_heads = W_qkv * z1ss + u1ss -> bf16 ws
    gemm_kernel<<<dim3(QLEN / 64, QKV3 / 64, BSZ), 256, 0, stream>>>(
        Wqkv, 2, z1ss, 2, (size_t)D_MODEL * QLEN,
        wh, (size_t)QKV3 * QLEN, 1,
        u1ss, 2, (size_t)QKV3 * QLEN,
        nullptr, 0,
        QKV3, QLEN, D_MODEL, flag);

    // 2. r_head_k = W_r * pos_emb -> bf16 ws
    gemm_kernel<<<dim3(QLEN / 64, D_MODEL / 64, 1), 256, 0, stream>>>(
        Wr, 2, pos, 2, 0,
        rhk, 0, 1,
        nullptr, 0, 0,
        nullptr, 0,
        D_MODEL, QLEN, D_MODEL, flag);

    // 3. banded attention with fused rel-shift -> attn_vec bf16
    attn_kernel<<<dim3(QLEN / 64, N_HEAD, BSZ), 256, 0, stream>>>(
        wh, rhk, rwb, rrb, avec, flag);

    // 4. y = W_o * attn_vec + b_o + z1ss -> fp32 ws
    gemm_kernel<<<dim3(QLEN / 64, D_MODEL / 64, BSZ), 256, 0, stream>>>(
        Wo, 2, avec, 0, (size_t)D_MODEL * QLEN,
        y, (size_t)D_MODEL * QLEN, 0,
        z1ss, 2, (size_t)D_MODEL * QLEN,
        bo, 2,
        D_MODEL, QLEN, D_MODEL, flag);

    // 5. LayerNorm over d_model -> out (dtype per flag)
    ln_kernel<<<dim3(QLEN / 64, BSZ), 256, 0, stream>>>(y, d_out, flag);
}

// Round 3
// 1667.795 us; speedup vs baseline: 1.3618x; 1.3618x over previous
//
#include <hip/hip_runtime.h>
#include <hip/hip_bf16.h>

#define D_MODEL 1024
#define N_HEAD 16
#define BSZ 2
#define QLEN 2048
#define LOCAL_SIZE 1000
#define QKV3 (3 * N_HEAD * 64) // 3072

typedef __hip_bfloat16 bf16;
typedef short bf16x8 __attribute__((ext_vector_type(8)));
typedef float f32x4 __attribute__((ext_vector_type(4)));

static __device__ __forceinline__ float b2f(bf16 x) { return __bfloat162float(x); }
static __device__ __forceinline__ float bits2f(unsigned short u) {
    return __uint_as_float(((unsigned int)u) << 16);
}
static __device__ __forceinline__ unsigned short f2bs(float x) {
    __hip_bfloat16 h = __float2bfloat16(x);
    return *(unsigned short*)&h;
}

// mode: 0 = always bf16, 1 = always fp32, 2 = follow runtime flag (raw harness tensor)
static __device__ __forceinline__ int rmode(int m, int fl) { return (m == 2) ? fl : m; }
static __device__ __forceinline__ float ldm(const void* p, size_t i, int isf) {
    return isf ? ((const float*)p)[i] : b2f(((const bf16*)p)[i]);
}
// vectorized 4-element load at element index i (i % 4 == 0)
static __device__ __forceinline__ float4 ld4(const void* p, size_t i, int isf) {
    if (isf) return ((const float4*)p)[i >> 2];
    ushort4 u = ((const ushort4*)p)[i >> 2];
    float4 f;
    f.x = bits2f(u.x); f.y = bits2f(u.y); f.z = bits2f(u.z); f.w = bits2f(u.w);
    return f;
}
static __device__ __forceinline__ ushort4 cvt4(float4 f) {
    ushort4 u;
    u.x = f2bs(f.x); u.y = f2bs(f.y); u.z = f2bs(f.z); u.w = f2bs(f.w);
    return u;
}

// ---------------------------------------------------------------------------
// dtype detector (flag: 0 = bf16 data, 1 = fp32 data). Proven in round 2.
// ---------------------------------------------------------------------------
__global__ void detect_kernel(const unsigned short* __restrict__ w, int* __restrict__ flag)
{
    if (threadIdx.x == 0 && blockIdx.x == 0) {
        int good = 0;
        for (int i = 0; i < 256; ++i) {
            float v = bits2f(w[i]);
            if (v == v && fabsf(v) < 8.0f) ++good;
        }
        *flag = (good >= 240) ? 0 : 1;
    }
}

// ---------------------------------------------------------------------------
// MFMA TN-GEMM: C[b][m][n] = sum_k A[b][m][k] * Bsrc(k,n)  (+ add)(+ bias[n])
//   A: [M][K] rows, K-contiguous (batched by sAb elems; raw dtype per mA)
//   Bsrc: bTrans=0 -> [N][K] rows (ldB=K); bTrans=1 -> [K][N] (ldB=N)
//   C: row-major [M][N], bf16 or fp32
//   add: addT=0 -> add[b][m][n]; addT=1 -> add[b][n*M + m]
// Tile 128x128, BK=32, 256 threads (4 waves, 2x2 wave grid, 4x4 MFMA each).
// mfma_f32_16x16x32_bf16 layouts (learn_hip-verified):
//   A-op: lane L holds A[m=L&15][k=(L>>4)*8+j]; B-op: B[k=(L>>4)*8+j][n=L&15]
//   C/D:  lane L reg r -> D[row=(L>>4)*4+r][col=L&15]
// ---------------------------------------------------------------------------
__global__ __launch_bounds__(256)
void gemm_tn(const void* __restrict__ A, int mA, size_t sAb,
             const void* __restrict__ Bsrc, int mB, int bTrans, int ldB, size_t sBb,
             void* __restrict__ C, int c_is_bf16, size_t sCb,
             const void* __restrict__ addm, int mAdd, int addT, size_t sAddb,
             const void* __restrict__ bias, int mBias,
             int M, int N, int K, const int* __restrict__ flag)
{
    const int fl = *flag;
    const int fA = rmode(mA, fl), fB = rmode(mB, fl);
    const int fAdd = rmode(mAdd, fl), fBias = rmode(mBias, fl);

    const int bz = blockIdx.z;
    const int n0 = blockIdx.x * 128;
    const int m0 = blockIdx.y * 128;
    const int tid = threadIdx.x;
    const int wave = tid >> 6, lane = tid & 63;
    const int quad = lane >> 4, l15 = lane & 15;
    const int wm = (wave >> 1) * 64, wn = (wave & 1) * 64;

    __shared__ unsigned short A_s[128][40]; // [m][k], +8 pad (row=80B, 16B-aligned)
    __shared__ unsigned short B_s[128][40]; // [n][k]

    const size_t aBase = (size_t)bz * sAb;
    const size_t bBase = (size_t)bz * sBb;

    f32x4 acc[4][4];
#pragma unroll
    for (int i = 0; i < 4; ++i)
#pragma unroll
        for (int j = 0; j < 4; ++j) acc[i][j] = (f32x4){0.f, 0.f, 0.f, 0.f};

    for (int k0 = 0; k0 < K; k0 += 32) {
        // stage A tile: 128 x 32, 4 elems per chunk
#pragma unroll
        for (int g = 0; g < 4; ++g) {
            int c = tid + g * 256;          // 0..1023
            int m = c >> 3, kc = (c & 7) * 4;
            float4 f = ld4(A, aBase + (size_t)(m0 + m) * K + k0 + kc, fA);
            *(ushort4*)&A_s[m][kc] = cvt4(f);
        }
        // stage B tile
        if (!bTrans) {
#pragma unroll
            for (int g = 0; g < 4; ++g) {
                int c = tid + g * 256;
                int n = c >> 3, kc = (c & 7) * 4;
                float4 f = ld4(Bsrc, bBase + (size_t)(n0 + n) * ldB + k0 + kc, fB);
                *(ushort4*)&B_s[n][kc] = cvt4(f);
            }
        } else {
            // source [K][N]: read 4 consecutive n, scatter-transpose into LDS
#pragma unroll
            for (int g = 0; g < 4; ++g) {
                int c = tid + g * 256;
                int k = c >> 5, nc = (c & 31) * 4;
                float4 f = ld4(Bsrc, bBase + (size_t)(k0 + k) * ldB + n0 + nc, fB);
                ushort4 u = cvt4(f);
                B_s[nc + 0][k] = u.x;
                B_s[nc + 1][k] = u.y;
                B_s[nc + 2][k] = u.z;
                B_s[nc + 3][k] = u.w;
            }
        }
        __syncthreads();

        bf16x8 a[4], bb[4];
#pragma unroll
        for (int i = 0; i < 4; ++i)
            a[i] = *(const bf16x8*)&A_s[wm + i * 16 + l15][quad * 8];
#pragma unroll
        for (int j = 0; j < 4; ++j)
            bb[j] = *(const bf16x8*)&B_s[wn + j * 16 + l15][quad * 8];
#pragma unroll
        for (int i = 0; i < 4; ++i)
#pragma unroll
            for (int j = 0; j < 4; ++j)
                acc[i][j] = __builtin_amdgcn_mfma_f32_16x16x32_bf16(a[i], bb[j], acc[i][j], 0, 0, 0);
        __syncthreads();
    }

    const size_t cb = (size_t)bz * sCb;
#pragma unroll
    for (int i = 0; i < 4; ++i) {
#pragma unroll
        for (int j = 0; j < 4; ++j) {
            int n = n0 + wn + j * 16 + l15;
#pragma unroll
            for (int r = 0; r < 4; ++r) {
                int m = m0 + wm + i * 16 + quad * 4 + r;
                float v = acc[i][j][r];
                if (addm) {
                    size_t ai = (size_t)bz * sAddb +
                                (addT ? ((size_t)n * M + m) : ((size_t)m * N + n));
                    v += ldm(addm, ai, fAdd);
                }
                if (bias) v += ldm(bias, (size_t)n, fBias);
                size_t ci = cb + (size_t)m * N + n;
                if (c_is_bf16) ((bf16*)C)[ci] = __float2bfloat16(v);
                else           ((float*)C)[ci] = v;
            }
        }
    }
}

// ---------------------------------------------------------------------------
// Flash-style banded attention with fused rel-shift (unchanged from the
// passing round-2 kernel except the OUTPUT STORE, now transposed:
// avec_t[b][q][h*64+d]).
// ---------------------------------------------------------------------------
__global__ __launch_bounds__(256)
void attn_kernel(const bf16* __restrict__ wh,  // [B][3072][Q]
                 const bf16* __restrict__ rhk, // [1024][Q]
                 const void* __restrict__ rwb, // [1024] raw
                 const void* __restrict__ rrb, // [1024] raw
                 bf16* __restrict__ av_out,    // [B][Q][1024] (transposed!)
                 const int* __restrict__ flag)
{
    const int fl = *flag;
    const int it = blockIdx.x;
    const int h  = blockIdx.y;
    const int b  = blockIdx.z;
    const int i0 = it * 64;
    const int tid = threadIdx.x;
    const int tx = tid & 15, ty = tid >> 4;

    __shared__ bf16 qrw[64][66];
    __shared__ bf16 qrr[64][66];
    __shared__ bf16 kt[64][66];
    __shared__ bf16 vt[64][66];
    __shared__ bf16 rt[64][128];
    __shared__ bf16 Pt[64][66];
    __shared__ float red[64][17];
    __shared__ float m_s[64], l_s[64], al_s[64];

    const size_t whB = (size_t)b * QKV3 * QLEN;

    for (int idx = tid; idx < 64 * 64; idx += 256) {
        int d = idx >> 6, ii = idx & 63;
        float q = b2f(wh[whB + (size_t)(h * 64 + d) * QLEN + i0 + ii]);
        qrw[d][ii] = __float2bfloat16(q + ldm(rwb, h * 64 + d, fl));
        qrr[d][ii] = __float2bfloat16(q + ldm(rrb, h * 64 + d, fl));
    }
    if (tid < 64) { m_s[tid] = -INFINITY; l_s[tid] = 0.f; }

    float O[4][4] = {};

    int lo = i0 - (LOCAL_SIZE - 1);
    if (lo < 0) lo = 0;
    const int jt_lo = lo >> 6;
    const int jt_hi = (i0 + 63) >> 6;
    const float scale = 0.125f;

    for (int jt = jt_lo; jt <= jt_hi; ++jt) {
        const int j0 = jt * 64;
        __syncthreads();
        for (int idx = tid; idx < 64 * 64; idx += 256) {
            int d = idx >> 6, jj = idx & 63;
            kt[d][jj] = wh[whB + (size_t)(1024 + h * 64 + d) * QLEN + j0 + jj];
            vt[jj][d] = wh[whB + (size_t)(2048 + h * 64 + d) * QLEN + j0 + jj];
        }
        const int pbase = j0 - i0 + QLEN - 1 - 63;
        for (int idx = tid; idx < 64 * 127; idx += 256) {
            int d = idx / 127, t = idx % 127;
            int p = pbase + t;
            bf16 v = __float2bfloat16(0.f);
            if (p >= 0 && p < QLEN) v = rhk[(size_t)(h * 64 + d) * QLEN + p];
            rt[d][t] = v;
        }
        __syncthreads();

        float s[4][4];
#pragma unroll
        for (int a = 0; a < 4; ++a)
#pragma unroll
            for (int c = 0; c < 4; ++c) s[a][c] = 0.f;
        const int tb = tx * 4 - ty * 4 + 63;
        for (int d = 0; d < 64; ++d) {
            float a1[4], a2[4], kv[4], rv[7];
#pragma unroll
            for (int a = 0; a < 4; ++a) {
                a1[a] = b2f(qrw[d][ty * 4 + a]);
                a2[a] = b2f(qrr[d][ty * 4 + a]);
            }
#pragma unroll
            for (int c = 0; c < 4; ++c) kv[c] = b2f(kt[d][tx * 4 + c]);
#pragma unroll
            for (int u = 0; u < 7; ++u) rv[u] = b2f(rt[d][tb - 3 + u]);
#pragma unroll
            for (int a = 0; a < 4; ++a)
#pragma unroll
                for (int c = 0; c < 4; ++c)
                    s[a][c] += a1[a] * kv[c] + a2[a] * rv[c - a + 3];
        }

#pragma unroll
        for (int a = 0; a < 4; ++a) {
            int i = i0 + ty * 4 + a;
            float mx = -INFINITY;
#pragma unroll
            for (int c = 0; c < 4; ++c) {
                int j = j0 + tx * 4 + c;
                int diff = i - j;
                if (diff < 0 || diff >= LOCAL_SIZE) s[a][c] = -INFINITY;
                else s[a][c] *= scale;
                mx = fmaxf(mx, s[a][c]);
            }
            red[ty * 4 + a][tx] = mx;
        }
        __syncthreads();
        if (tid < 64) {
            float mo = m_s[tid];
            float t = -INFINITY;
            for (int c = 0; c < 16; ++c) t = fmaxf(t, red[tid][c]);
            float mn = fmaxf(mo, t);
            m_s[tid] = mn;
            al_s[tid] = (mo == -INFINITY) ? 0.f : __expf(mo - mn);
        }
        __syncthreads();

#pragma unroll
        for (int a = 0; a < 4; ++a) {
            int ii = ty * 4 + a;
            float mn = m_s[ii];
            float sum = 0.f;
#pragma unroll
            for (int c = 0; c < 4; ++c) {
                float p = (mn == -INFINITY) ? 0.f : __expf(s[a][c] - mn);
                Pt[ii][tx * 4 + c] = __float2bfloat16(p);
                sum += p;
            }
            red[ii][tx] = sum;
        }
        __syncthreads();
        if (tid < 64) {
            float sum = 0.f;
            for (int c = 0; c < 16; ++c) sum += red[tid][c];
            l_s[tid] = l_s[tid] * al_s[tid] + sum;
        }

#pragma unroll
        for (int a = 0; a < 4; ++a) {
            float f = al_s[ty * 4 + a];
#pragma unroll
            for (int c = 0; c < 4; ++c) O[a][c] *= f;
        }
        for (int jj = 0; jj < 64; ++jj) {
            float pv[4];
#pragma unroll
            for (int a = 0; a < 4; ++a) pv[a] = b2f(Pt[ty * 4 + a][jj]);
#pragma unroll
            for (int c = 0; c < 4; ++c) {
                float vv = b2f(vt[jj][tx * 4 + c]);
#pragma unroll
                for (int a = 0; a < 4; ++a) O[a][c] += pv[a] * vv;
            }
        }
    }
    __syncthreads();

#pragma unroll
    for (int a = 0; a < 4; ++a) {
        int ii = ty * 4 + a;
        float inv = 1.f / l_s[ii];
#pragma unroll
        for (int c = 0; c < 4; ++c) {
            int d = tx * 4 + c;
            av_out[(size_t)b * QLEN * D_MODEL + (size_t)(i0 + ii) * D_MODEL + h * 64 + d] =
                __float2bfloat16(O[a][c] * inv);
        }
    }
}

// ---------------------------------------------------------------------------
// Row LayerNorm in place: y_t[b][q][0..1024) fp32, one block per (b,q).
// ---------------------------------------------------------------------------
__global__ __launch_bounds__(256)
void ln_kernel(float* __restrict__ yt)
{
    const int b = blockIdx.y, q = blockIdx.x;
    float* row = yt + ((size_t)b * QLEN + q) * D_MODEL;
    const int t = threadIdx.x;
    float4 v = ((float4*)row)[t];
    float s  = v.x + v.y + v.z + v.w;
    float ss = v.x * v.x + v.y * v.y + v.z * v.z + v.w * v.w;
#pragma unroll
    for (int off = 32; off; off >>= 1) {
        s  += __shfl_down(s, off);
        ss += __shfl_down(ss, off);
    }
    __shared__ float sw[4], ssw[4];
    const int w = t >> 6;
    if ((t & 63) == 0) { sw[w] = s; ssw[w] = ss; }
    __syncthreads();
    float S  = sw[0] + sw[1] + sw[2] + sw[3];
    float SS = ssw[0] + ssw[1] + ssw[2] + ssw[3];
    float mu  = S / D_MODEL;
    float var = SS / D_MODEL - mu * mu;
    float rs  = rsqrtf(var + 1e-5f);
    v.x = (v.x - mu) * rs; v.y = (v.y - mu) * rs;
    v.z = (v.z - mu) * rs; v.w = (v.w - mu) * rs;
    ((float4*)row)[t] = v;
}

// ---------------------------------------------------------------------------
// Transpose y_t[b][q][o] fp32 -> out[b][o][q] (dtype per flag). 32x32 tiles.
// ---------------------------------------------------------------------------
__global__ __launch_bounds__(256)
void transpose_out(const float* __restrict__ yt, void* __restrict__ out,
                   const int* __restrict__ flag)
{
    const int fl = *flag;
    const int b  = blockIdx.z;
    const int q0 = blockIdx.x * 32;
    const int o0 = blockIdx.y * 32;
    const int tx = threadIdx.x & 31, ty = threadIdx.x >> 5;
    __shared__ float T[32][33];
#pragma unroll
    for (int r = 0; r < 4; ++r) {
        int q = q0 + ty + r * 8;
        T[ty + r * 8][tx] = yt[((size_t)b * QLEN + q) * D_MODEL + o0 + tx];
    }
    __syncthreads();
#pragma unroll
    for (int r = 0; r < 4; ++r) {
        int o = o0 + ty + r * 8;
        size_t oi = ((size_t)b * D_MODEL + o) * QLEN + q0 + tx;
        float v = T[tx][ty + r * 8];
        if (fl) ((float*)out)[oi] = v;
        else    ((bf16*)out)[oi] = __float2bfloat16(v);
    }
}

// ---------------------------------------------------------------------------
extern "C" void kernel_launch(void* const* d_in, const int* in_sizes, int n_in,
                              void* d_out, int out_size, void* d_ws, size_t ws_size,
                              hipStream_t stream)
{
    const void* z1ss = d_in[0]; // [B][1024][Q] raw
    const void* pos  = d_in[1]; // [1][1024][Q] raw
    const void* u1ss = d_in[2]; // [B][3072][Q] raw
    const void* Wqkv = d_in[3]; // [3072][1024] raw
    const void* Wr   = d_in[4]; // [1024][1024] raw
    const void* rwb  = d_in[5]; // [1024] raw
    const void* rrb  = d_in[6]; // [1024] raw
    const void* Wo   = d_in[7]; // [1024][1024] raw
    const void* bo   = d_in[8]; // [1024] raw

    // workspace layout (byte-identical footprint to the proven round-2 layout)
    char* ws = (char*)d_ws;
    bf16* wh = (bf16*)ws;                               // [B][3072][Q]   25,165,824 B
    size_t off = (size_t)BSZ * QKV3 * QLEN * sizeof(bf16);
    bf16* rhk = (bf16*)(ws + off);                      // [1024][Q]       4,194,304 B
    off += (size_t)D_MODEL * QLEN * sizeof(bf16);
    bf16* avec = (bf16*)(ws + off);                     // [B][Q][1024]    8,388,608 B
    off += (size_t)BSZ * D_MODEL * QLEN * sizeof(bf16);
    int* flag = (int*)(ws + off);
    float* yt = (float*)ws; // overlays wh (dead after attn): [B][Q][1024] fp32 16.8 MB

    detect_kernel<<<1, 64, 0, stream>>>((const unsigned short*)Wqkv, flag);

    // 1. wh[b][o][q] = Wqkv(o,:) . z1ss[b](:,q) + u1ss   (M=3072, N=2048, K=1024)
    gemm_tn<<<dim3(2048 / 128, 3072 / 128, BSZ), 256, 0, stream>>>(
        Wqkv, 2, 0,
        z1ss, 2, 1, QLEN, (size_t)D_MODEL * QLEN,
        wh, 1, (size_t)QKV3 * QLEN,
        u1ss, 2, 0, (size_t)QKV3 * QLEN,
        nullptr, 0,
        QKV3, QLEN, D_MODEL, flag);

    // 2. rhk[o][q] = Wr(o,:) . pos(:,q)                  (M=1024, N=2048, K=1024)
    gemm_tn<<<dim3(2048 / 128, 1024 / 128, 1), 256, 0, stream>>>(
        Wr, 2, 0,
        pos, 2, 1, QLEN, 0,
        rhk, 1, 0,
        nullptr, 0, 0, 0,
        nullptr, 0,
        D_MODEL, QLEN, D_MODEL, flag);

    // 3. banded flash attention -> avec_t[b][q][1024]
    attn_kernel<<<dim3(QLEN / 64, N_HEAD, BSZ), 256, 0, stream>>>(
        wh, rhk, rwb, rrb, avec, flag);

    // 4. y_t[b][q][o] = avec_t[b](q,:) . Wo(o,:) + bo[o] + z1ss[b][o][q]
    //    (M=2048, N=1024, K=1024; fp32 out, overlays wh)
    gemm_tn<<<dim3(1024 / 128, 2048 / 128, BSZ), 256, 0, stream>>>(
        avec, 0, (size_t)QLEN * D_MODEL,
        Wo, 2, 0, D_MODEL, 0,
        yt, 0, (size_t)QLEN * D_MODEL,
        z1ss, 2, 1, (size_t)D_MODEL * QLEN,
        bo, 2,
        QLEN, D_MODEL, D_MODEL, flag);

    // 5. LN in place on y_t rows
    ln_kernel<<<dim3(QLEN, BSZ), 256, 0, stream>>>(yt);

    // 6. transpose to out[b][o][q] (dtype per flag)
    transpose_out<<<dim3(QLEN / 32, D_MODEL / 32, BSZ), 256, 0, stream>>>(yt, d_out, flag);
}

// Round 4
// 846.868 us; speedup vs baseline: 2.6819x; 1.9694x over previous
//
#include <hip/hip_runtime.h>
#include <hip/hip_bf16.h>

#define D_MODEL 1024
#define N_HEAD 16
#define BSZ 2
#define QLEN 2048
#define LOCAL_SIZE 1000
#define QKV3 (3 * N_HEAD * 64) // 3072

typedef __hip_bfloat16 bf16;
typedef short bf16x8 __attribute__((ext_vector_type(8)));
typedef float f32x4 __attribute__((ext_vector_type(4)));

static __device__ __forceinline__ float b2f(bf16 x) { return __bfloat162float(x); }
static __device__ __forceinline__ float bits2f(unsigned short u) {
    return __uint_as_float(((unsigned int)u) << 16);
}
static __device__ __forceinline__ unsigned short f2bs(float x) {
    __hip_bfloat16 h = __float2bfloat16(x);
    return *(unsigned short*)&h;
}

// mode: 0 = always bf16, 1 = always fp32, 2 = follow runtime flag (raw harness tensor)
static __device__ __forceinline__ int rmode(int m, int fl) { return (m == 2) ? fl : m; }
static __device__ __forceinline__ float ldm(const void* p, size_t i, int isf) {
    return isf ? ((const float*)p)[i] : b2f(((const bf16*)p)[i]);
}
static __device__ __forceinline__ float4 ld4(const void* p, size_t i, int isf) {
    if (isf) return ((const float4*)p)[i >> 2];
    ushort4 u = ((const ushort4*)p)[i >> 2];
    float4 f;
    f.x = bits2f(u.x); f.y = bits2f(u.y); f.z = bits2f(u.z); f.w = bits2f(u.w);
    return f;
}
static __device__ __forceinline__ ushort4 cvt4(float4 f) {
    ushort4 u;
    u.x = f2bs(f.x); u.y = f2bs(f.y); u.z = f2bs(f.z); u.w = f2bs(f.w);
    return u;
}

// ---------------------------------------------------------------------------
// dtype detector (flag: 0 = bf16 data, 1 = fp32 data). Proven in round 2.
// ---------------------------------------------------------------------------
__global__ void detect_kernel(const unsigned short* __restrict__ w, int* __restrict__ flag)
{
    if (threadIdx.x == 0 && blockIdx.x == 0) {
        int good = 0;
        for (int i = 0; i < 256; ++i) {
            float v = bits2f(w[i]);
            if (v == v && fabsf(v) < 8.0f) ++good;
        }
        *flag = (good >= 240) ? 0 : 1;
    }
}

// ---------------------------------------------------------------------------
// MFMA TN-GEMM (unchanged from round 3 — passing). 128x128 tile, BK=32.
// ---------------------------------------------------------------------------
__global__ __launch_bounds__(256)
void gemm_tn(const void* __restrict__ A, int mA, size_t sAb,
             const void* __restrict__ Bsrc, int mB, int bTrans, int ldB, size_t sBb,
             void* __restrict__ C, int c_is_bf16, size_t sCb,
             const void* __restrict__ addm, int mAdd, int addT, size_t sAddb,
             const void* __restrict__ bias, int mBias,
             int M, int N, int K, const int* __restrict__ flag)
{
    const int fl = *flag;
    const int fA = rmode(mA, fl), fB = rmode(mB, fl);
    const int fAdd = rmode(mAdd, fl), fBias = rmode(mBias, fl);

    const int bz = blockIdx.z;
    const int n0 = blockIdx.x * 128;
    const int m0 = blockIdx.y * 128;
    const int tid = threadIdx.x;
    const int wave = tid >> 6, lane = tid & 63;
    const int quad = lane >> 4, l15 = lane & 15;
    const int wm = (wave >> 1) * 64, wn = (wave & 1) * 64;

    __shared__ unsigned short A_s[128][40];
    __shared__ unsigned short B_s[128][40];

    const size_t aBase = (size_t)bz * sAb;
    const size_t bBase = (size_t)bz * sBb;

    f32x4 acc[4][4];
#pragma unroll
    for (int i = 0; i < 4; ++i)
#pragma unroll
        for (int j = 0; j < 4; ++j) acc[i][j] = (f32x4){0.f, 0.f, 0.f, 0.f};

    for (int k0 = 0; k0 < K; k0 += 32) {
#pragma unroll
        for (int g = 0; g < 4; ++g) {
            int c = tid + g * 256;
            int m = c >> 3, kc = (c & 7) * 4;
            float4 f = ld4(A, aBase + (size_t)(m0 + m) * K + k0 + kc, fA);
            *(ushort4*)&A_s[m][kc] = cvt4(f);
        }
        if (!bTrans) {
#pragma unroll
            for (int g = 0; g < 4; ++g) {
                int c = tid + g * 256;
                int n = c >> 3, kc = (c & 7) * 4;
                float4 f = ld4(Bsrc, bBase + (size_t)(n0 + n) * ldB + k0 + kc, fB);
                *(ushort4*)&B_s[n][kc] = cvt4(f);
            }
        } else {
#pragma unroll
            for (int g = 0; g < 4; ++g) {
                int c = tid + g * 256;
                int k = c >> 5, nc = (c & 31) * 4;
                float4 f = ld4(Bsrc, bBase + (size_t)(k0 + k) * ldB + n0 + nc, fB);
                ushort4 u = cvt4(f);
                B_s[nc + 0][k] = u.x;
                B_s[nc + 1][k] = u.y;
                B_s[nc + 2][k] = u.z;
                B_s[nc + 3][k] = u.w;
            }
        }
        __syncthreads();

        bf16x8 a[4], bb[4];
#pragma unroll
        for (int i = 0; i < 4; ++i)
            a[i] = *(const bf16x8*)&A_s[wm + i * 16 + l15][quad * 8];
#pragma unroll
        for (int j = 0; j < 4; ++j)
            bb[j] = *(const bf16x8*)&B_s[wn + j * 16 + l15][quad * 8];
#pragma unroll
        for (int i = 0; i < 4; ++i)
#pragma unroll
            for (int j = 0; j < 4; ++j)
                acc[i][j] = __builtin_amdgcn_mfma_f32_16x16x32_bf16(a[i], bb[j], acc[i][j], 0, 0, 0);
        __syncthreads();
    }

    const size_t cb = (size_t)bz * sCb;
#pragma unroll
    for (int i = 0; i < 4; ++i) {
#pragma unroll
        for (int j = 0; j < 4; ++j) {
            int n = n0 + wn + j * 16 + l15;
#pragma unroll
            for (int r = 0; r < 4; ++r) {
                int m = m0 + wm + i * 16 + quad * 4 + r;
                float v = acc[i][j][r];
                if (addm) {
                    size_t ai = (size_t)bz * sAddb +
                                (addT ? ((size_t)n * M + m) : ((size_t)m * N + n));
                    v += ldm(addm, ai, fAdd);
                }
                if (bias) v += ldm(bias, (size_t)n, fBias);
                size_t ci = cb + (size_t)m * N + n;
                if (c_is_bf16) ((bf16*)C)[ci] = __float2bfloat16(v);
                else           ((float*)C)[ci] = v;
            }
        }
    }
}

// ---------------------------------------------------------------------------
// MFMA banded flash attention with fused rel-shift.
// Block = 64 queries of one (b,h); 4 waves; wave w owns S-rows [w*16, w*16+16).
// Per j-tile: AC = qrw^T K (MFMA), G = qrr^T R_window (MFMA, 64x128),
// BD[i,j] = G[i][j-i+63] gathered from LDS, online softmax in registers,
// PV via MFMA with P routed through wave-local LDS rows.
// LDS 64,512 B (Rt overlaid by Gs after the G-MFMAs) -> 2 blocks/CU.
// ---------------------------------------------------------------------------
__global__ __launch_bounds__(256)
void attn_mfma(const bf16* __restrict__ wh,  // [B][3072][Q]
               const bf16* __restrict__ rhk, // [1024][Q]
               const void* __restrict__ rwb, // [1024] raw
               const void* __restrict__ rrb, // [1024] raw
               bf16* __restrict__ av_out,    // [B][Q][1024]
               const int* __restrict__ flag)
{
    const int fl = *flag;
    const int it = blockIdx.x, h = blockIdx.y, b = blockIdx.z;
    const int i0 = it * 64;
    const int tid = threadIdx.x;
    const int wave = tid >> 6, lane = tid & 63;
    const int quad = lane >> 4, l15 = lane & 15;
    const int hw = h * 64;

    // LDS layout (ushort units): rows padded to 72 (144 B, 16B-aligned, 2-way banks)
    __shared__ __align__(16) unsigned short sm[32256]; // 64,512 B
    unsigned short* Qrw = sm;          // [64][72]  q + r_w_bias, [i][d]
    unsigned short* Qrr = sm + 4608;   // [64][72]  q + r_r_bias, [i][d]
    unsigned short* Kt  = sm + 9216;   // [64][72]  K^T, [j][d]
    unsigned short* Vs  = sm + 13824;  // [64][72]  V, [d][j]
    unsigned short* Ps  = sm + 18432;  // [64][72]  P, [i][j]
    unsigned short* Rt  = sm + 23040;  // [128][72] R window, [t][d]
    unsigned short* Gs  = sm + 23040;  // [64][136] overlay (Rt dead after G-MFMAs)

    const bf16* whb = wh + (size_t)b * QKV3 * QLEN;
    const int d_t = tid & 63; // d-lane for transpose staging

    // ---- stage Q (once), add biases, transpose to [i][d] ----
    {
        float brw = ldm(rwb, hw + d_t, fl);
        float brr = ldm(rrb, hw + d_t, fl);
        const bf16* qrow = whb + (size_t)(hw + d_t) * QLEN + i0;
#pragma unroll
        for (int g = 0; g < 2; ++g) {
            int i8 = (g * 4 + wave) * 8;
            unsigned short u8[8];
            *(uint4*)u8 = *(const uint4*)(qrow + i8);
#pragma unroll
            for (int u = 0; u < 8; ++u) {
                float q = bits2f(u8[u]);
                Qrw[(i8 + u) * 72 + d_t] = f2bs(q + brw);
                Qrr[(i8 + u) * 72 + d_t] = f2bs(q + brr);
            }
        }
    }
    __syncthreads();

    // loop-invariant A-fragments (rows wave*16+l15 of Qrw/Qrr)
    const int qrow_off = (wave * 16 + l15) * 72 + quad * 8;
    bf16x8 qw0 = *(const bf16x8*)&Qrw[qrow_off];
    bf16x8 qw1 = *(const bf16x8*)&Qrw[qrow_off + 32];
    bf16x8 qr0 = *(const bf16x8*)&Qrr[qrow_off];
    bf16x8 qr1 = *(const bf16x8*)&Qrr[qrow_off + 32];

    float m_r[4], l_r[4];
    f32x4 o_acc[4];
#pragma unroll
    for (int r = 0; r < 4; ++r) { m_r[r] = -INFINITY; l_r[r] = 0.f; }
#pragma unroll
    for (int dj = 0; dj < 4; ++dj) o_acc[dj] = (f32x4){0.f, 0.f, 0.f, 0.f};

    int lo = i0 - (LOCAL_SIZE - 1);
    if (lo < 0) lo = 0;

    for (int jt = lo >> 6; jt <= it; ++jt) {
        const int j0 = jt * 64;
        __syncthreads(); // all waves done reading staging buffers of prev iter

        // ---- stage K^T [j][d] ----
        {
            const bf16* krow = whb + (size_t)(1024 + hw + d_t) * QLEN + j0;
#pragma unroll
            for (int g = 0; g < 2; ++g) {
                int j8 = (g * 4 + wave) * 8;
                unsigned short u8[8];
                *(uint4*)u8 = *(const uint4*)(krow + j8);
#pragma unroll
                for (int u = 0; u < 8; ++u) Kt[(j8 + u) * 72 + d_t] = u8[u];
            }
        }
        // ---- stage V [d][j] (no transpose) ----
#pragma unroll
        for (int g = 0; g < 2; ++g) {
            int c = g * 256 + tid;
            int d = c >> 3, j8 = (c & 7) * 8;
            *(uint4*)&Vs[d * 72 + j8] =
                *(const uint4*)(whb + (size_t)(2048 + hw + d) * QLEN + j0 + j8);
        }
        // ---- stage R window [t][d], t in [0,128), p = pbase + t ----
        {
            const int pbase = j0 - i0 + QLEN - 64;
            const bf16* rrow = rhk + (size_t)(hw + d_t) * QLEN;
#pragma unroll
            for (int g = 0; g < 4; ++g) {
                int t8 = (g * 4 + wave) * 8;
                int p = pbase + t8;
                unsigned short u8[8];
                if (p >= 0 && p + 7 < QLEN) {
                    *(uint4*)u8 = *(const uint4*)(rrow + p);
                } else {
#pragma unroll
                    for (int u = 0; u < 8; ++u) {
                        int pp = p + u;
                        u8[u] = (pp >= 0 && pp < QLEN) ? *(const unsigned short*)(rrow + pp) : 0;
                    }
                }
#pragma unroll
                for (int u = 0; u < 8; ++u) Rt[(t8 + u) * 72 + d_t] = u8[u];
            }
        }
        __syncthreads();

        // ---- AC MFMAs: S[m=i][n=j], K=64 ----
        f32x4 s_acc[4];
#pragma unroll
        for (int nj = 0; nj < 4; ++nj) {
            s_acc[nj] = (f32x4){0.f, 0.f, 0.f, 0.f};
            int ko = (nj * 16 + l15) * 72 + quad * 8;
            bf16x8 b0 = *(const bf16x8*)&Kt[ko];
            bf16x8 b1 = *(const bf16x8*)&Kt[ko + 32];
            s_acc[nj] = __builtin_amdgcn_mfma_f32_16x16x32_bf16(qw0, b0, s_acc[nj], 0, 0, 0);
            s_acc[nj] = __builtin_amdgcn_mfma_f32_16x16x32_bf16(qw1, b1, s_acc[nj], 0, 0, 0);
        }
        // ---- G MFMAs: G[m=i][n=t], K=64, t in [0,128) ----
        f32x4 g_acc[8];
#pragma unroll
        for (int nt = 0; nt < 8; ++nt) {
            g_acc[nt] = (f32x4){0.f, 0.f, 0.f, 0.f};
            int ro = (nt * 16 + l15) * 72 + quad * 8;
            bf16x8 b0 = *(const bf16x8*)&Rt[ro];
            bf16x8 b1 = *(const bf16x8*)&Rt[ro + 32];
            g_acc[nt] = __builtin_amdgcn_mfma_f32_16x16x32_bf16(qr0, b0, g_acc[nt], 0, 0, 0);
            g_acc[nt] = __builtin_amdgcn_mfma_f32_16x16x32_bf16(qr1, b1, g_acc[nt], 0, 0, 0);
        }
        __syncthreads(); // all waves done reading Rt before Gs overlay write

        // ---- write G to LDS (wave-local rows) ----
#pragma unroll
        for (int nt = 0; nt < 8; ++nt)
#pragma unroll
            for (int r = 0; r < 4; ++r)
                Gs[(wave * 16 + quad * 4 + r) * 136 + nt * 16 + l15] = f2bs(g_acc[nt][r]);
        // wave-local read-after-write: same-wave LDS ops are in-order; no barrier

        // ---- gather BD, mask, scale ----
        float sv[4][4]; // [nj][r]
#pragma unroll
        for (int nj = 0; nj < 4; ++nj) {
#pragma unroll
            for (int r = 0; r < 4; ++r) {
                int i_loc = wave * 16 + quad * 4 + r;
                int j_loc = nj * 16 + l15;
                int t = j_loc - i_loc + 63; // always in [0,126]
                float bd = bits2f(Gs[i_loc * 136 + t]);
                int diff = (i0 + i_loc) - (j0 + j_loc);
                sv[nj][r] = (diff < 0 || diff >= LOCAL_SIZE)
                                ? -INFINITY
                                : (s_acc[nj][r] + bd) * 0.125f;
            }
        }

        // ---- online softmax (rows wave-local; reduce over l15 group) ----
        float mnew[4], alpha[4];
#pragma unroll
        for (int r = 0; r < 4; ++r) {
            float tm = fmaxf(fmaxf(sv[0][r], sv[1][r]), fmaxf(sv[2][r], sv[3][r]));
            tm = fmaxf(tm, __shfl_xor(tm, 1));
            tm = fmaxf(tm, __shfl_xor(tm, 2));
            tm = fmaxf(tm, __shfl_xor(tm, 4));
            tm = fmaxf(tm, __shfl_xor(tm, 8));
            mnew[r] = fmaxf(m_r[r], tm);
            alpha[r] = (m_r[r] == -INFINITY) ? 0.f : __expf(m_r[r] - mnew[r]);
        }
#pragma unroll
        for (int r = 0; r < 4; ++r) {
            float rs = 0.f;
#pragma unroll
            for (int nj = 0; nj < 4; ++nj) {
                float p = (mnew[r] == -INFINITY) ? 0.f : __expf(sv[nj][r] - mnew[r]);
                Ps[(wave * 16 + quad * 4 + r) * 72 + nj * 16 + l15] = f2bs(p);
                rs += p;
            }
            rs += __shfl_xor(rs, 1);
            rs += __shfl_xor(rs, 2);
            rs += __shfl_xor(rs, 4);
            rs += __shfl_xor(rs, 8);
            l_r[r] = l_r[r] * alpha[r] + rs;
            m_r[r] = mnew[r];
        }
#pragma unroll
        for (int dj = 0; dj < 4; ++dj)
#pragma unroll
            for (int r = 0; r < 4; ++r) o_acc[dj][r] *= alpha[r];

        // ---- PV MFMAs: O[m=i][n=d] += P[m][k=j] V[k=j][n=d] ----
        {
            int po = (wave * 16 + l15) * 72 + quad * 8;
            bf16x8 pa0 = *(const bf16x8*)&Ps[po];
            bf16x8 pa1 = *(const bf16x8*)&Ps[po + 32];
#pragma unroll
            for (int dj = 0; dj < 4; ++dj) {
                int vo = (dj * 16 + l15) * 72 + quad * 8;
                bf16x8 b0 = *(const bf16x8*)&Vs[vo];
                bf16x8 b1 = *(const bf16x8*)&Vs[vo + 32];
                o_acc[dj] = __builtin_amdgcn_mfma_f32_16x16x32_bf16(pa0, b0, o_acc[dj], 0, 0, 0);
                o_acc[dj] = __builtin_amdgcn_mfma_f32_16x16x32_bf16(pa1, b1, o_acc[dj], 0, 0, 0);
            }
        }
    }

    // ---- normalize and store (transposed layout [b][q][h*64+d]) ----
#pragma unroll
    for (int r = 0; r < 4; ++r) {
        float inv = 1.f / l_r[r];
        int q = i0 + wave * 16 + quad * 4 + r;
        bf16* orow = av_out + ((size_t)b * QLEN + q) * D_MODEL + hw;
#pragma unroll
        for (int dj = 0; dj < 4; ++dj)
            orow[dj * 16 + l15] = __float2bfloat16(o_acc[dj][r] * inv);
    }
}

// ---------------------------------------------------------------------------
// Row LayerNorm in place: y_t[b][q][0..1024) fp32, one block per (b,q).
// ---------------------------------------------------------------------------
__global__ __launch_bounds__(256)
void ln_kernel(float* __restrict__ yt)
{
    const int b = blockIdx.y, q = blockIdx.x;
    float* row = yt + ((size_t)b * QLEN + q) * D_MODEL;
    const int t = threadIdx.x;
    float4 v = ((float4*)row)[t];
    float s  = v.x + v.y + v.z + v.w;
    float ss = v.x * v.x + v.y * v.y + v.z * v.z + v.w * v.w;
#pragma unroll
    for (int off = 32; off; off >>= 1) {
        s  += __shfl_down(s, off);
        ss += __shfl_down(ss, off);
    }
    __shared__ float sw[4], ssw[4];
    const int w = t >> 6;
    if ((t & 63) == 0) { sw[w] = s; ssw[w] = ss; }
    __syncthreads();
    float S  = sw[0] + sw[1] + sw[2] + sw[3];
    float SS = ssw[0] + ssw[1] + ssw[2] + ssw[3];
    float mu  = S / D_MODEL;
    float var = SS / D_MODEL - mu * mu;
    float rs  = rsqrtf(var + 1e-5f);
    v.x = (v.x - mu) * rs; v.y = (v.y - mu) * rs;
    v.z = (v.z - mu) * rs; v.w = (v.w - mu) * rs;
    ((float4*)row)[t] = v;
}

// ---------------------------------------------------------------------------
// Transpose y_t[b][q][o] fp32 -> out[b][o][q] (dtype per flag). 32x32 tiles.
// ---------------------------------------------------------------------------
__global__ __launch_bounds__(256)
void transpose_out(const float* __restrict__ yt, void* __restrict__ out,
                   const int* __restrict__ flag)
{
    const int fl = *flag;
    const int b  = blockIdx.z;
    const int q0 = blockIdx.x * 32;
    const int o0 = blockIdx.y * 32;
    const int tx = threadIdx.x & 31, ty = threadIdx.x >> 5;
    __shared__ float T[32][33];
#pragma unroll
    for (int r = 0; r < 4; ++r) {
        int q = q0 + ty + r * 8;
        T[ty + r * 8][tx] = yt[((size_t)b * QLEN + q) * D_MODEL + o0 + tx];
    }
    __syncthreads();
#pragma unroll
    for (int r = 0; r < 4; ++r) {
        int o = o0 + ty + r * 8;
        size_t oi = ((size_t)b * D_MODEL + o) * QLEN + q0 + tx;
        float v = T[tx][ty + r * 8];
        if (fl) ((float*)out)[oi] = v;
        else    ((bf16*)out)[oi] = __float2bfloat16(v);
    }
}

// ---------------------------------------------------------------------------
extern "C" void kernel_launch(void* const* d_in, const int* in_sizes, int n_in,
                              void* d_out, int out_size, void* d_ws, size_t ws_size,
                              hipStream_t stream)
{
    const void* z1ss = d_in[0];
    const void* pos  = d_in[1];
    const void* u1ss = d_in[2];
    const void* Wqkv = d_in[3];
    const void* Wr   = d_in[4];
    const void* rwb  = d_in[5];
    const void* rrb  = d_in[6];
    const void* Wo   = d_in[7];
    const void* bo   = d_in[8];

    char* ws = (char*)d_ws;
    bf16* wh = (bf16*)ws;                               // [B][3072][Q]
    size_t off = (size_t)BSZ * QKV3 * QLEN * sizeof(bf16);
    bf16* rhk = (bf16*)(ws + off);                      // [1024][Q]
    off += (size_t)D_MODEL * QLEN * sizeof(bf16);
    bf16* avec = (bf16*)(ws + off);                     // [B][Q][1024]
    off += (size_t)BSZ * D_MODEL * QLEN * sizeof(bf16);
    int* flag = (int*)(ws + off);
    float* yt = (float*)ws; // overlays wh (dead after attn)

    detect_kernel<<<1, 64, 0, stream>>>((const unsigned short*)Wqkv, flag);

    // 1. wh[b][o][q] = Wqkv(o,:) . z1ss[b](:,q) + u1ss
    gemm_tn<<<dim3(2048 / 128, 3072 / 128, BSZ), 256, 0, stream>>>(
        Wqkv, 2, 0,
        z1ss, 2, 1, QLEN, (size_t)D_MODEL * QLEN,
        wh, 1, (size_t)QKV3 * QLEN,
        u1ss, 2, 0, (size_t)QKV3 * QLEN,
        nullptr, 0,
        QKV3, QLEN, D_MODEL, flag);

    // 2. rhk[o][q] = Wr(o,:) . pos(:,q)
    gemm_tn<<<dim3(2048 / 128, 1024 / 128, 1), 256, 0, stream>>>(
        Wr, 2, 0,
        pos, 2, 1, QLEN, 0,
        rhk, 1, 0,
        nullptr, 0, 0, 0,
        nullptr, 0,
        D_MODEL, QLEN, D_MODEL, flag);

    // 3. MFMA banded flash attention -> avec_t[b][q][1024]
    attn_mfma<<<dim3(QLEN / 64, N_HEAD, BSZ), 256, 0, stream>>>(
        wh, rhk, rwb, rrb, avec, flag);

    // 4. y_t[b][q][o] = avec_t[b](q,:) . Wo(o,:) + bo[o] + z1ss[b][o][q]
    gemm_tn<<<dim3(1024 / 128, 2048 / 128, BSZ), 256, 0, stream>>>(
        avec, 0, (size_t)QLEN * D_MODEL,
        Wo, 2, 0, D_MODEL, 0,
        yt, 0, (size_t)QLEN * D_MODEL,
        z1ss, 2, 1, (size_t)D_MODEL * QLEN,
        bo, 2,
        QLEN, D_MODEL, D_MODEL, flag);

    // 5. LN in place on y_t rows
    ln_kernel<<<dim3(QLEN, BSZ), 256, 0, stream>>>(yt);

    // 6. transpose to out[b][o][q]
    transpose_out<<<dim3(QLEN / 32, D_MODEL / 32, BSZ), 256, 0, stream>>>(yt, d_out, flag);
}

// Round 5
// 780.621 us; speedup vs baseline: 2.9095x; 1.0849x over previous
//
#include <hip/hip_runtime.h>
#include <hip/hip_bf16.h>

#define D_MODEL 1024
#define N_HEAD 16
#define BSZ 2
#define QLEN 2048
#define LOCAL_SIZE 1000
#define QKV3 (3 * N_HEAD * 64) // 3072

typedef __hip_bfloat16 bf16;
typedef short bf16x8 __attribute__((ext_vector_type(8)));
typedef float f32x4 __attribute__((ext_vector_type(4)));

static __device__ __forceinline__ float b2f(bf16 x) { return __bfloat162float(x); }
static __device__ __forceinline__ float bits2f(unsigned short u) {
    return __uint_as_float(((unsigned int)u) << 16);
}
static __device__ __forceinline__ unsigned short f2bs(float x) {
    __hip_bfloat16 h = __float2bfloat16(x);
    return *(unsigned short*)&h;
}

// mode: 0 = always bf16, 1 = always fp32, 2 = follow runtime flag (raw harness tensor)
static __device__ __forceinline__ int rmode(int m, int fl) { return (m == 2) ? fl : m; }
static __device__ __forceinline__ float ldm(const void* p, size_t i, int isf) {
    return isf ? ((const float*)p)[i] : b2f(((const bf16*)p)[i]);
}
static __device__ __forceinline__ float4 ld4(const void* p, size_t i, int isf) {
    if (isf) return ((const float4*)p)[i >> 2];
    ushort4 u = ((const ushort4*)p)[i >> 2];
    float4 f;
    f.x = bits2f(u.x); f.y = bits2f(u.y); f.z = bits2f(u.z); f.w = bits2f(u.w);
    return f;
}
static __device__ __forceinline__ ushort4 cvt4(float4 f) {
    ushort4 u;
    u.x = f2bs(f.x); u.y = f2bs(f.y); u.z = f2bs(f.z); u.w = f2bs(f.w);
    return u;
}

// ---------------------------------------------------------------------------
// dtype detector (flag: 0 = bf16 data, 1 = fp32 data). Proven in round 2.
// ---------------------------------------------------------------------------
__global__ void detect_kernel(const unsigned short* __restrict__ w, int* __restrict__ flag)
{
    if (threadIdx.x == 0 && blockIdx.x == 0) {
        int good = 0;
        for (int i = 0; i < 256; ++i) {
            float v = bits2f(w[i]);
            if (v == v && fabsf(v) < 8.0f) ++good;
        }
        *flag = (good >= 240) ? 0 : 1;
    }
}

// ---------------------------------------------------------------------------
// Transpose + convert: in[b][rows][cols] (raw dtype per flag) -> out[b][cols][rows] bf16.
// 32x32 tiles, coalesced both sides.
// ---------------------------------------------------------------------------
__global__ __launch_bounds__(256)
void transpose_cvt(const void* __restrict__ in, bf16* __restrict__ outp,
                   int rows, int cols, size_t sIn, size_t sOut,
                   const int* __restrict__ flag)
{
    const int fl = *flag;
    const int b  = blockIdx.z;
    const int c0 = blockIdx.x * 32;
    const int r0 = blockIdx.y * 32;
    const int tx = threadIdx.x & 31, ty = threadIdx.x >> 5;
    __shared__ float T[32][33];
#pragma unroll
    for (int r = 0; r < 4; ++r) {
        int rr = r0 + ty + r * 8;
        T[ty + r * 8][tx] = ldm(in, (size_t)b * sIn + (size_t)rr * cols + c0 + tx, fl);
    }
    __syncthreads();
#pragma unroll
    for (int r = 0; r < 4; ++r) {
        int cc = c0 + ty + r * 8;
        outp[(size_t)b * sOut + (size_t)cc * rows + r0 + tx] =
            __float2bfloat16(T[tx][ty + r * 8]);
    }
}

// ---------------------------------------------------------------------------
// MFMA TN-GEMM. 128x128 tile, BK=32. bTrans=1 path kept only for the
// small-workspace fallback (it has heavy LDS bank conflicts).
// ---------------------------------------------------------------------------
__global__ __launch_bounds__(256)
void gemm_tn(const void* __restrict__ A, int mA, size_t sAb,
             const void* __restrict__ Bsrc, int mB, int bTrans, int ldB, size_t sBb,
             void* __restrict__ C, int c_is_bf16, size_t sCb,
             const void* __restrict__ addm, int mAdd, int addT, size_t sAddb,
             const void* __restrict__ bias, int mBias,
             int M, int N, int K, const int* __restrict__ flag)
{
    const int fl = *flag;
    const int fA = rmode(mA, fl), fB = rmode(mB, fl);
    const int fAdd = rmode(mAdd, fl), fBias = rmode(mBias, fl);

    const int bz = blockIdx.z;
    const int n0 = blockIdx.x * 128;
    const int m0 = blockIdx.y * 128;
    const int tid = threadIdx.x;
    const int wave = tid >> 6, lane = tid & 63;
    const int quad = lane >> 4, l15 = lane & 15;
    const int wm = (wave >> 1) * 64, wn = (wave & 1) * 64;

    __shared__ unsigned short A_s[128][40];
    __shared__ unsigned short B_s[128][40];

    const size_t aBase = (size_t)bz * sAb;
    const size_t bBase = (size_t)bz * sBb;

    f32x4 acc[4][4];
#pragma unroll
    for (int i = 0; i < 4; ++i)
#pragma unroll
        for (int j = 0; j < 4; ++j) acc[i][j] = (f32x4){0.f, 0.f, 0.f, 0.f};

    for (int k0 = 0; k0 < K; k0 += 32) {
#pragma unroll
        for (int g = 0; g < 4; ++g) {
            int c = tid + g * 256;
            int m = c >> 3, kc = (c & 7) * 4;
            float4 f = ld4(A, aBase + (size_t)(m0 + m) * K + k0 + kc, fA);
            *(ushort4*)&A_s[m][kc] = cvt4(f);
        }
        if (!bTrans) {
#pragma unroll
            for (int g = 0; g < 4; ++g) {
                int c = tid + g * 256;
                int n = c >> 3, kc = (c & 7) * 4;
                float4 f = ld4(Bsrc, bBase + (size_t)(n0 + n) * ldB + k0 + kc, fB);
                *(ushort4*)&B_s[n][kc] = cvt4(f);
            }
        } else {
#pragma unroll
            for (int g = 0; g < 4; ++g) {
                int c = tid + g * 256;
                int k = c >> 5, nc = (c & 31) * 4;
                float4 f = ld4(Bsrc, bBase + (size_t)(k0 + k) * ldB + n0 + nc, fB);
                ushort4 u = cvt4(f);
                B_s[nc + 0][k] = u.x;
                B_s[nc + 1][k] = u.y;
                B_s[nc + 2][k] = u.z;
                B_s[nc + 3][k] = u.w;
            }
        }
        __syncthreads();

        bf16x8 a[4], bb[4];
#pragma unroll
        for (int i = 0; i < 4; ++i)
            a[i] = *(const bf16x8*)&A_s[wm + i * 16 + l15][quad * 8];
#pragma unroll
        for (int j = 0; j < 4; ++j)
            bb[j] = *(const bf16x8*)&B_s[wn + j * 16 + l15][quad * 8];
#pragma unroll
        for (int i = 0; i < 4; ++i)
#pragma unroll
            for (int j = 0; j < 4; ++j)
                acc[i][j] = __builtin_amdgcn_mfma_f32_16x16x32_bf16(a[i], bb[j], acc[i][j], 0, 0, 0);
        __syncthreads();
    }

    const size_t cb = (size_t)bz * sCb;
#pragma unroll
    for (int i = 0; i < 4; ++i) {
#pragma unroll
        for (int j = 0; j < 4; ++j) {
            int n = n0 + wn + j * 16 + l15;
#pragma unroll
            for (int r = 0; r < 4; ++r) {
                int m = m0 + wm + i * 16 + quad * 4 + r;
                float v = acc[i][j][r];
                if (addm) {
                    size_t ai = (size_t)bz * sAddb +
                                (addT ? ((size_t)n * M + m) : ((size_t)m * N + n));
                    v += ldm(addm, ai, fAdd);
                }
                if (bias) v += ldm(bias, (size_t)n, fBias);
                size_t ci = cb + (size_t)m * N + n;
                if (c_is_bf16) ((bf16*)C)[ci] = __float2bfloat16(v);
                else           ((float*)C)[ci] = v;
            }
        }
    }
}

// ---------------------------------------------------------------------------
// MFMA banded flash attention with fused rel-shift (unchanged — passing).
// ---------------------------------------------------------------------------
__global__ __launch_bounds__(256)
void attn_mfma(const bf16* __restrict__ wh,  // [B][3072][Q]
               const bf16* __restrict__ rhk, // [1024][Q]
               const void* __restrict__ rwb, // [1024] raw
               const void* __restrict__ rrb, // [1024] raw
               bf16* __restrict__ av_out,    // [B][Q][1024]
               const int* __restrict__ flag)
{
    const int fl = *flag;
    const int it = blockIdx.x, h = blockIdx.y, b = blockIdx.z;
    const int i0 = it * 64;
    const int tid = threadIdx.x;
    const int wave = tid >> 6, lane = tid & 63;
    const int quad = lane >> 4, l15 = lane & 15;
    const int hw = h * 64;

    __shared__ __align__(16) unsigned short sm[32256]; // 64,512 B
    unsigned short* Qrw = sm;          // [64][72]
    unsigned short* Qrr = sm + 4608;   // [64][72]
    unsigned short* Kt  = sm + 9216;   // [64][72]
    unsigned short* Vs  = sm + 13824;  // [64][72]
    unsigned short* Ps  = sm + 18432;  // [64][72]
    unsigned short* Rt  = sm + 23040;  // [128][72]
    unsigned short* Gs  = sm + 23040;  // [64][136] overlay

    const bf16* whb = wh + (size_t)b * QKV3 * QLEN;
    const int d_t = tid & 63;

    {
        float brw = ldm(rwb, hw + d_t, fl);
        float brr = ldm(rrb, hw + d_t, fl);
        const bf16* qrow = whb + (size_t)(hw + d_t) * QLEN + i0;
#pragma unroll
        for (int g = 0; g < 2; ++g) {
            int i8 = (g * 4 + wave) * 8;
            unsigned short u8[8];
            *(uint4*)u8 = *(const uint4*)(qrow + i8);
#pragma unroll
            for (int u = 0; u < 8; ++u) {
                float q = bits2f(u8[u]);
                Qrw[(i8 + u) * 72 + d_t] = f2bs(q + brw);
                Qrr[(i8 + u) * 72 + d_t] = f2bs(q + brr);
            }
        }
    }
    __syncthreads();

    const int qrow_off = (wave * 16 + l15) * 72 + quad * 8;
    bf16x8 qw0 = *(const bf16x8*)&Qrw[qrow_off];
    bf16x8 qw1 = *(const bf16x8*)&Qrw[qrow_off + 32];
    bf16x8 qr0 = *(const bf16x8*)&Qrr[qrow_off];
    bf16x8 qr1 = *(const bf16x8*)&Qrr[qrow_off + 32];

    float m_r[4], l_r[4];
    f32x4 o_acc[4];
#pragma unroll
    for (int r = 0; r < 4; ++r) { m_r[r] = -INFINITY; l_r[r] = 0.f; }
#pragma unroll
    for (int dj = 0; dj < 4; ++dj) o_acc[dj] = (f32x4){0.f, 0.f, 0.f, 0.f};

    int lo = i0 - (LOCAL_SIZE - 1);
    if (lo < 0) lo = 0;

    for (int jt = lo >> 6; jt <= it; ++jt) {
        const int j0 = jt * 64;
        __syncthreads();

        {
            const bf16* krow = whb + (size_t)(1024 + hw + d_t) * QLEN + j0;
#pragma unroll
            for (int g = 0; g < 2; ++g) {
                int j8 = (g * 4 + wave) * 8;
                unsigned short u8[8];
                *(uint4*)u8 = *(const uint4*)(krow + j8);
#pragma unroll
                for (int u = 0; u < 8; ++u) Kt[(j8 + u) * 72 + d_t] = u8[u];
            }
        }
#pragma unroll
        for (int g = 0; g < 2; ++g) {
            int c = g * 256 + tid;
            int d = c >> 3, j8 = (c & 7) * 8;
            *(uint4*)&Vs[d * 72 + j8] =
                *(const uint4*)(whb + (size_t)(2048 + hw + d) * QLEN + j0 + j8);
        }
        {
            const int pbase = j0 - i0 + QLEN - 64;
            const bf16* rrow = rhk + (size_t)(hw + d_t) * QLEN;
#pragma unroll
            for (int g = 0; g < 4; ++g) {
                int t8 = (g * 4 + wave) * 8;
                int p = pbase + t8;
                unsigned short u8[8];
                if (p >= 0 && p + 7 < QLEN) {
                    *(uint4*)u8 = *(const uint4*)(rrow + p);
                } else {
#pragma unroll
                    for (int u = 0; u < 8; ++u) {
                        int pp = p + u;
                        u8[u] = (pp >= 0 && pp < QLEN) ? *(const unsigned short*)(rrow + pp) : 0;
                    }
                }
#pragma unroll
                for (int u = 0; u < 8; ++u) Rt[(t8 + u) * 72 + d_t] = u8[u];
            }
        }
        __syncthreads();

        f32x4 s_acc[4];
#pragma unroll
        for (int nj = 0; nj < 4; ++nj) {
            s_acc[nj] = (f32x4){0.f, 0.f, 0.f, 0.f};
            int ko = (nj * 16 + l15) * 72 + quad * 8;
            bf16x8 b0 = *(const bf16x8*)&Kt[ko];
            bf16x8 b1 = *(const bf16x8*)&Kt[ko + 32];
            s_acc[nj] = __builtin_amdgcn_mfma_f32_16x16x32_bf16(qw0, b0, s_acc[nj], 0, 0, 0);
            s_acc[nj] = __builtin_amdgcn_mfma_f32_16x16x32_bf16(qw1, b1, s_acc[nj], 0, 0, 0);
        }
        f32x4 g_acc[8];
#pragma unroll
        for (int nt = 0; nt < 8; ++nt) {
            g_acc[nt] = (f32x4){0.f, 0.f, 0.f, 0.f};
            int ro = (nt * 16 + l15) * 72 + quad * 8;
            bf16x8 b0 = *(const bf16x8*)&Rt[ro];
            bf16x8 b1 = *(const bf16x8*)&Rt[ro + 32];
            g_acc[nt] = __builtin_amdgcn_mfma_f32_16x16x32_bf16(qr0, b0, g_acc[nt], 0, 0, 0);
            g_acc[nt] = __builtin_amdgcn_mfma_f32_16x16x32_bf16(qr1, b1, g_acc[nt], 0, 0, 0);
        }
        __syncthreads();

#pragma unroll
        for (int nt = 0; nt < 8; ++nt)
#pragma unroll
            for (int r = 0; r < 4; ++r)
                Gs[(wave * 16 + quad * 4 + r) * 136 + nt * 16 + l15] = f2bs(g_acc[nt][r]);

        float sv[4][4];
#pragma unroll
        for (int nj = 0; nj < 4; ++nj) {
#pragma unroll
            for (int r = 0; r < 4; ++r) {
                int i_loc = wave * 16 + quad * 4 + r;
                int j_loc = nj * 16 + l15;
                int t = j_loc - i_loc + 63;
                float bd = bits2f(Gs[i_loc * 136 + t]);
                int diff = (i0 + i_loc) - (j0 + j_loc);
                sv[nj][r] = (diff < 0 || diff >= LOCAL_SIZE)
                                ? -INFINITY
                                : (s_acc[nj][r] + bd) * 0.125f;
            }
        }

        float mnew[4], alpha[4];
#pragma unroll
        for (int r = 0; r < 4; ++r) {
            float tm = fmaxf(fmaxf(sv[0][r], sv[1][r]), fmaxf(sv[2][r], sv[3][r]));
            tm = fmaxf(tm, __shfl_xor(tm, 1));
            tm = fmaxf(tm, __shfl_xor(tm, 2));
            tm = fmaxf(tm, __shfl_xor(tm, 4));
            tm = fmaxf(tm, __shfl_xor(tm, 8));
            mnew[r] = fmaxf(m_r[r], tm);
            alpha[r] = (m_r[r] == -INFINITY) ? 0.f : __expf(m_r[r] - mnew[r]);
        }
#pragma unroll
        for (int r = 0; r < 4; ++r) {
            float rs = 0.f;
#pragma unroll
            for (int nj = 0; nj < 4; ++nj) {
                float p = (mnew[r] == -INFINITY) ? 0.f : __expf(sv[nj][r] - mnew[r]);
                Ps[(wave * 16 + quad * 4 + r) * 72 + nj * 16 + l15] = f2bs(p);
                rs += p;
            }
            rs += __shfl_xor(rs, 1);
            rs += __shfl_xor(rs, 2);
            rs += __shfl_xor(rs, 4);
            rs += __shfl_xor(rs, 8);
            l_r[r] = l_r[r] * alpha[r] + rs;
            m_r[r] = mnew[r];
        }
#pragma unroll
        for (int dj = 0; dj < 4; ++dj)
#pragma unroll
            for (int r = 0; r < 4; ++r) o_acc[dj][r] *= alpha[r];

        {
            int po = (wave * 16 + l15) * 72 + quad * 8;
            bf16x8 pa0 = *(const bf16x8*)&Ps[po];
            bf16x8 pa1 = *(const bf16x8*)&Ps[po + 32];
#pragma unroll
            for (int dj = 0; dj < 4; ++dj) {
                int vo = (dj * 16 + l15) * 72 + quad * 8;
                bf16x8 b0 = *(const bf16x8*)&Vs[vo];
                bf16x8 b1 = *(const bf16x8*)&Vs[vo + 32];
                o_acc[dj] = __builtin_amdgcn_mfma_f32_16x16x32_bf16(pa0, b0, o_acc[dj], 0, 0, 0);
                o_acc[dj] = __builtin_amdgcn_mfma_f32_16x16x32_bf16(pa1, b1, o_acc[dj], 0, 0, 0);
            }
        }
    }

#pragma unroll
    for (int r = 0; r < 4; ++r) {
        float inv = 1.f / l_r[r];
        int q = i0 + wave * 16 + quad * 4 + r;
        bf16* orow = av_out + ((size_t)b * QLEN + q) * D_MODEL + hw;
#pragma unroll
        for (int dj = 0; dj < 4; ++dj)
            orow[dj * 16 + l15] = __float2bfloat16(o_acc[dj][r] * inv);
    }
}

// ---------------------------------------------------------------------------
// Row LayerNorm in place (unchanged).
// ---------------------------------------------------------------------------
__global__ __launch_bounds__(256)
void ln_kernel(float* __restrict__ yt)
{
    const int b = blockIdx.y, q = blockIdx.x;
    float* row = yt + ((size_t)b * QLEN + q) * D_MODEL;
    const int t = threadIdx.x;
    float4 v = ((float4*)row)[t];
    float s  = v.x + v.y + v.z + v.w;
    float ss = v.x * v.x + v.y * v.y + v.z * v.z + v.w * v.w;
#pragma unroll
    for (int off = 32; off; off >>= 1) {
        s  += __shfl_down(s, off);
        ss += __shfl_down(ss, off);
    }
    __shared__ float sw[4], ssw[4];
    const int w = t >> 6;
    if ((t & 63) == 0) { sw[w] = s; ssw[w] = ss; }
    __syncthreads();
    float S  = sw[0] + sw[1] + sw[2] + sw[3];
    float SS = ssw[0] + ssw[1] + ssw[2] + ssw[3];
    float mu  = S / D_MODEL;
    float var = SS / D_MODEL - mu * mu;
    float rs  = rsqrtf(var + 1e-5f);
    v.x = (v.x - mu) * rs; v.y = (v.y - mu) * rs;
    v.z = (v.z - mu) * rs; v.w = (v.w - mu) * rs;
    ((float4*)row)[t] = v;
}

// ---------------------------------------------------------------------------
// Transpose y_t[b][q][o] fp32 -> out[b][o][q] (dtype per flag). Unchanged.
// ---------------------------------------------------------------------------
__global__ __launch_bounds__(256)
void transpose_out(const float* __restrict__ yt, void* __restrict__ out,
                   const int* __restrict__ flag)
{
    const int fl = *flag;
    const int b  = blockIdx.z;
    const int q0 = blockIdx.x * 32;
    const int o0 = blockIdx.y * 32;
    const int tx = threadIdx.x & 31, ty = threadIdx.x >> 5;
    __shared__ float T[32][33];
#pragma unroll
    for (int r = 0; r < 4; ++r) {
        int q = q0 + ty + r * 8;
        T[ty + r * 8][tx] = yt[((size_t)b * QLEN + q) * D_MODEL + o0 + tx];
    }
    __syncthreads();
#pragma unroll
    for (int r = 0; r < 4; ++r) {
        int o = o0 + ty + r * 8;
        size_t oi = ((size_t)b * D_MODEL + o) * QLEN + q0 + tx;
        float v = T[tx][ty + r * 8];
        if (fl) ((float*)out)[oi] = v;
        else    ((bf16*)out)[oi] = __float2bfloat16(v);
    }
}

// ---------------------------------------------------------------------------
extern "C" void kernel_launch(void* const* d_in, const int* in_sizes, int n_in,
                              void* d_out, int out_size, void* d_ws, size_t ws_size,
                              hipStream_t stream)
{
    const void* z1ss = d_in[0];
    const void* pos  = d_in[1];
    const void* u1ss = d_in[2];
    const void* Wqkv = d_in[3];
    const void* Wr   = d_in[4];
    const void* rwb  = d_in[5];
    const void* rrb  = d_in[6];
    const void* Wo   = d_in[7];
    const void* bo   = d_in[8];

    const size_t whE  = (size_t)BSZ * QKV3 * QLEN;     // 12,582,912
    const size_t rhkE = (size_t)D_MODEL * QLEN;        //  2,097,152
    const size_t avE  = (size_t)BSZ * QLEN * D_MODEL;  //  4,194,304
    const size_t ztE  = avE;

    char* ws = (char*)d_ws;
    bf16* wh   = (bf16*)ws;
    bf16* rhk  = wh + whE;
    bf16* avec = rhk + rhkE;
    bf16* post = avec; // overlay: post dead before attn writes avec
    size_t baseB = (whE + rhkE + avE) * sizeof(bf16);  // 37,748,736
    const bool big = ws_size >= baseB + ztE * sizeof(bf16) + 16;
    bf16* zt = (bf16*)(ws + baseB);
    int* flag = (int*)(ws + baseB + (big ? ztE * sizeof(bf16) : 0));
    float* yt = (float*)ws; // overlays wh (dead after attn)

    detect_kernel<<<1, 64, 0, stream>>>((const unsigned short*)Wqkv, flag);

    if (big) {
        // 0. pre-transpose: zt[b][q][d] = z1ss^T (bf16), post[q][d] = pos^T (bf16)
        transpose_cvt<<<dim3(QLEN / 32, D_MODEL / 32, BSZ), 256, 0, stream>>>(
            z1ss, zt, D_MODEL, QLEN, (size_t)D_MODEL * QLEN, (size_t)QLEN * D_MODEL, flag);
        transpose_cvt<<<dim3(QLEN / 32, D_MODEL / 32, 1), 256, 0, stream>>>(
            pos, post, D_MODEL, QLEN, 0, 0, flag);

        // 1. wh[b][o][q] = Wqkv(o,:) . zt[b](q,:) + u1ss   (B no-trans, conflict-free)
        gemm_tn<<<dim3(2048 / 128, 3072 / 128, BSZ), 256, 0, stream>>>(
            Wqkv, 2, 0,
            zt, 0, 0, D_MODEL, (size_t)QLEN * D_MODEL,
            wh, 1, (size_t)QKV3 * QLEN,
            u1ss, 2, 0, (size_t)QKV3 * QLEN,
            nullptr, 0,
            QKV3, QLEN, D_MODEL, flag);

        // 2. rhk[o][q] = Wr(o,:) . post(q,:)
        gemm_tn<<<dim3(2048 / 128, 1024 / 128, 1), 256, 0, stream>>>(
            Wr, 2, 0,
            post, 0, 0, D_MODEL, 0,
            rhk, 1, 0,
            nullptr, 0, 0, 0,
            nullptr, 0,
            D_MODEL, QLEN, D_MODEL, flag);

        // 3. MFMA banded flash attention -> avec_t[b][q][1024] (overwrites post)
        attn_mfma<<<dim3(QLEN / 64, N_HEAD, BSZ), 256, 0, stream>>>(
            wh, rhk, rwb, rrb, avec, flag);

        // 4. y_t[b][q][o] = avec_t[b](q,:) . Wo(o,:) + bo[o] + zt[b][q][o]
        gemm_tn<<<dim3(1024 / 128, 2048 / 128, BSZ), 256, 0, stream>>>(
            avec, 0, (size_t)QLEN * D_MODEL,
            Wo, 2, 0, D_MODEL, 0,
            yt, 0, (size_t)QLEN * D_MODEL,
            zt, 0, 0, (size_t)QLEN * D_MODEL,
            bo, 2,
            QLEN, D_MODEL, D_MODEL, flag);
    } else {
        // fallback: proven round-4 path (in-GEMM transpose)
        gemm_tn<<<dim3(2048 / 128, 3072 / 128, BSZ), 256, 0, stream>>>(
            Wqkv, 2, 0,
            z1ss, 2, 1, QLEN, (size_t)D_MODEL * QLEN,
            wh, 1, (size_t)QKV3 * QLEN,
            u1ss, 2, 0, (size_t)QKV3 * QLEN,
            nullptr, 0,
            QKV3, QLEN, D_MODEL, flag);
        gemm_tn<<<dim3(2048 / 128, 1024 / 128, 1), 256, 0, stream>>>(
            Wr, 2, 0,
            pos, 2, 1, QLEN, 0,
            rhk, 1, 0,
            nullptr, 0, 0, 0,
            nullptr, 0,
            D_MODEL, QLEN, D_MODEL, flag);
        attn_mfma<<<dim3(QLEN / 64, N_HEAD, BSZ), 256, 0, stream>>>(
            wh, rhk, rwb, rrb, avec, flag);
        gemm_tn<<<dim3(1024 / 128, 2048 / 128, BSZ), 256, 0, stream>>>(
            avec, 0, (size_t)QLEN * D_MODEL,
            Wo, 2, 0, D_MODEL, 0,
            yt, 0, (size_t)QLEN * D_MODEL,
            z1ss, 2, 1, (size_t)D_MODEL * QLEN,
            bo, 2,
            QLEN, D_MODEL, D_MODEL, flag);
    }

    // 5. LN in place on y_t rows
    ln_kernel<<<dim3(QLEN, BSZ), 256, 0, stream>>>(yt);

    // 6. transpose to out[b][o][q]
    transpose_out<<<dim3(QLEN / 32, D_MODEL / 32, BSZ), 256, 0, stream>>>(yt, d_out, flag);
}

// Round 6
// 542.372 us; speedup vs baseline: 4.1876x; 1.4393x over previous
//
#include <hip/hip_runtime.h>
#include <hip/hip_bf16.h>

#define D_MODEL 1024
#define N_HEAD 16
#define BSZ 2
#define QLEN 2048
#define LOCAL_SIZE 1000
#define QKV3 (3 * N_HEAD * 64) // 3072

typedef __hip_bfloat16 bf16;
typedef short bf16x8 __attribute__((ext_vector_type(8)));
typedef float f32x4 __attribute__((ext_vector_type(4)));

static __device__ __forceinline__ float b2f(bf16 x) { return __bfloat162float(x); }
static __device__ __forceinline__ float bits2f(unsigned short u) {
    return __uint_as_float(((unsigned int)u) << 16);
}
static __device__ __forceinline__ unsigned short f2bs(float x) {
    __hip_bfloat16 h = __float2bfloat16(x);
    return *(unsigned short*)&h;
}

// mode: 0 = always bf16, 1 = always fp32, 2 = follow runtime flag (raw harness tensor)
static __device__ __forceinline__ int rmode(int m, int fl) { return (m == 2) ? fl : m; }
static __device__ __forceinline__ float ldm(const void* p, size_t i, int isf) {
    return isf ? ((const float*)p)[i] : b2f(((const bf16*)p)[i]);
}
static __device__ __forceinline__ float4 ld4(const void* p, size_t i, int isf) {
    if (isf) return ((const float4*)p)[i >> 2];
    ushort4 u = ((const ushort4*)p)[i >> 2];
    float4 f;
    f.x = bits2f(u.x); f.y = bits2f(u.y); f.z = bits2f(u.z); f.w = bits2f(u.w);
    return f;
}
static __device__ __forceinline__ ushort4 cvt4(float4 f) {
    ushort4 u;
    u.x = f2bs(f.x); u.y = f2bs(f.y); u.z = f2bs(f.z); u.w = f2bs(f.w);
    return u;
}

// ---------------------------------------------------------------------------
// dtype detector (flag: 0 = bf16 data, 1 = fp32 data). Proven in round 2.
// ---------------------------------------------------------------------------
__global__ void detect_kernel(const unsigned short* __restrict__ w, int* __restrict__ flag)
{
    if (threadIdx.x == 0 && blockIdx.x == 0) {
        int good = 0;
        for (int i = 0; i < 256; ++i) {
            float v = bits2f(w[i]);
            if (v == v && fabsf(v) < 8.0f) ++good;
        }
        *flag = (good >= 240) ? 0 : 1;
    }
}

// ---------------------------------------------------------------------------
// Transpose + convert: in[b][rows][cols] (raw) -> out[b][cols][rows] bf16.
// ---------------------------------------------------------------------------
__global__ __launch_bounds__(256)
void transpose_cvt(const void* __restrict__ in, bf16* __restrict__ outp,
                   int rows, int cols, size_t sIn, size_t sOut,
                   const int* __restrict__ flag)
{
    const int fl = *flag;
    const int b  = blockIdx.z;
    const int c0 = blockIdx.x * 32;
    const int r0 = blockIdx.y * 32;
    const int tx = threadIdx.x & 31, ty = threadIdx.x >> 5;
    __shared__ float T[32][33];
#pragma unroll
    for (int r = 0; r < 4; ++r) {
        int rr = r0 + ty + r * 8;
        T[ty + r * 8][tx] = ldm(in, (size_t)b * sIn + (size_t)rr * cols + c0 + tx, fl);
    }
    __syncthreads();
#pragma unroll
    for (int r = 0; r < 4; ++r) {
        int cc = c0 + ty + r * 8;
        outp[(size_t)b * sOut + (size_t)cc * rows + r0 + tx] =
            __float2bfloat16(T[tx][ty + r * 8]);
    }
}

// ---------------------------------------------------------------------------
// Software-pipelined MFMA TN-GEMM: C[b][m][n] = A[b][m][k] * B[b][n][k] (+add)(+bias)
// A, B: K-major rows; dtype per mode (0=bf16, 2=flag). 128x128 tile, BK=32.
// Per iter: write(prev regs)->LDS; barrier; ISSUE next loads (batched, no use);
// ds_read frags + 16 MFMA (loads fly behind compute); barrier.
// ---------------------------------------------------------------------------
__global__ __launch_bounds__(256)
void gemm_bf16(const void* __restrict__ A, int mA, size_t sAb,
               const void* __restrict__ B, int mB, size_t sBb,
               void* __restrict__ C, int c_is_bf16, size_t sCb,
               const void* __restrict__ addm, int mAdd, size_t sAddb,
               const void* __restrict__ bias, int mBias,
               int M, int N, int K, const int* __restrict__ flag)
{
    const int fl = *flag;
    const int fA = rmode(mA, fl), fB = rmode(mB, fl);
    const int fAdd = rmode(mAdd, fl), fBias = rmode(mBias, fl);

    const int bz = blockIdx.z;
    const int n0 = blockIdx.x * 128;
    const int m0 = blockIdx.y * 128;
    const int tid = threadIdx.x;
    const int wave = tid >> 6, lane = tid & 63;
    const int quad = lane >> 4, l15 = lane & 15;
    const int wm = (wave >> 1) * 64, wn = (wave & 1) * 64;

    __shared__ unsigned short A_s[128][40];
    __shared__ unsigned short B_s[128][40];

    // chunk j in [0,512): row = j>>2, c = j&3 (16B bf16 chunk = 8 elems)
    const int r0c = tid >> 2,        c0c = tid & 3;
    const int r1c = (tid + 256) >> 2, c1c = tid & 3; // (tid+256)&3 == tid&3

    const size_t aOff = (size_t)bz * sAb;
    const size_t bOff = (size_t)bz * sBb;
    const bf16*  Ah = (const bf16*)A;
    const float* Af = (const float*)A;
    const bf16*  Bh = (const bf16*)B;
    const float* Bf = (const float*)B;

    uint4 pa[4], pb[4];

#define LOAD_OP(p, fX, Xh, Xf, xOff, R0, C0, R1, C1, base, k0)                          \
    do {                                                                                \
        if (!fX) {                                                                      \
            p[0] = *(const uint4*)(Xh + xOff + (size_t)(base + R0) * K + (k0) + C0 * 8);\
            p[1] = *(const uint4*)(Xh + xOff + (size_t)(base + R1) * K + (k0) + C1 * 8);\
        } else {                                                                        \
            const float* q0 = Xf + xOff + (size_t)(base + R0) * K + (k0) + C0 * 8;      \
            const float* q1 = Xf + xOff + (size_t)(base + R1) * K + (k0) + C1 * 8;      \
            p[0] = *(const uint4*)q0; p[1] = *(const uint4*)(q0 + 4);                   \
            p[2] = *(const uint4*)q1; p[3] = *(const uint4*)(q1 + 4);                   \
        }                                                                               \
    } while (0)

#define WRITE_OP(p, fX, S, R0, C0, R1, C1)                                              \
    do {                                                                                \
        if (!fX) {                                                                      \
            *(uint4*)&S[R0][C0 * 8] = p[0];                                             \
            *(uint4*)&S[R1][C1 * 8] = p[1];                                             \
        } else {                                                                        \
            float4 f0 = *(float4*)&p[0], f1 = *(float4*)&p[1];                          \
            float4 f2 = *(float4*)&p[2], f3 = *(float4*)&p[3];                          \
            *(ushort4*)&S[R0][C0 * 8]     = cvt4(f0);                                   \
            *(ushort4*)&S[R0][C0 * 8 + 4] = cvt4(f1);                                   \
            *(ushort4*)&S[R1][C1 * 8]     = cvt4(f2);                                   \
            *(ushort4*)&S[R1][C1 * 8 + 4] = cvt4(f3);                                   \
        }                                                                               \
    } while (0)

    f32x4 acc[4][4];
#pragma unroll
    for (int i = 0; i < 4; ++i)
#pragma unroll
        for (int j = 0; j < 4; ++j) acc[i][j] = (f32x4){0.f, 0.f, 0.f, 0.f};

    LOAD_OP(pa, fA, Ah, Af, aOff, r0c, c0c, r1c, c1c, m0, 0);
    LOAD_OP(pb, fB, Bh, Bf, bOff, r0c, c0c, r1c, c1c, n0, 0);

    for (int k0 = 0; k0 < K; k0 += 32) {
        WRITE_OP(pa, fA, A_s, r0c, c0c, r1c, c1c);
        WRITE_OP(pb, fB, B_s, r0c, c0c, r1c, c1c);
        __syncthreads();

        const int kn = k0 + 32;
        if (kn < K) {
            LOAD_OP(pa, fA, Ah, Af, aOff, r0c, c0c, r1c, c1c, m0, kn);
            LOAD_OP(pb, fB, Bh, Bf, bOff, r0c, c0c, r1c, c1c, n0, kn);
        }

        bf16x8 a[4], bb[4];
#pragma unroll
        for (int i = 0; i < 4; ++i)
            a[i] = *(const bf16x8*)&A_s[wm + i * 16 + l15][quad * 8];
#pragma unroll
        for (int j = 0; j < 4; ++j)
            bb[j] = *(const bf16x8*)&B_s[wn + j * 16 + l15][quad * 8];
#pragma unroll
        for (int i = 0; i < 4; ++i)
#pragma unroll
            for (int j = 0; j < 4; ++j)
                acc[i][j] = __builtin_amdgcn_mfma_f32_16x16x32_bf16(a[i], bb[j], acc[i][j], 0, 0, 0);
        __syncthreads();
    }
#undef LOAD_OP
#undef WRITE_OP

    const size_t cb = (size_t)bz * sCb;
#pragma unroll
    for (int i = 0; i < 4; ++i) {
#pragma unroll
        for (int j = 0; j < 4; ++j) {
            int n = n0 + wn + j * 16 + l15;
#pragma unroll
            for (int r = 0; r < 4; ++r) {
                int m = m0 + wm + i * 16 + quad * 4 + r;
                float v = acc[i][j][r];
                if (addm) v += ldm(addm, (size_t)bz * sAddb + (size_t)m * N + n, fAdd);
                if (bias) v += ldm(bias, (size_t)n, fBias);
                size_t ci = cb + (size_t)m * N + n;
                if (c_is_bf16) ((bf16*)C)[ci] = __float2bfloat16(v);
                else           ((float*)C)[ci] = v;
            }
        }
    }
}

// ---------------------------------------------------------------------------
// Old MFMA TN-GEMM (kept for small-workspace fallback path only).
// ---------------------------------------------------------------------------
__global__ __launch_bounds__(256)
void gemm_tn(const void* __restrict__ A, int mA, size_t sAb,
             const void* __restrict__ Bsrc, int mB, int bTrans, int ldB, size_t sBb,
             void* __restrict__ C, int c_is_bf16, size_t sCb,
             const void* __restrict__ addm, int mAdd, int addT, size_t sAddb,
             const void* __restrict__ bias, int mBias,
             int M, int N, int K, const int* __restrict__ flag)
{
    const int fl = *flag;
    const int fA = rmode(mA, fl), fB = rmode(mB, fl);
    const int fAdd = rmode(mAdd, fl), fBias = rmode(mBias, fl);

    const int bz = blockIdx.z;
    const int n0 = blockIdx.x * 128;
    const int m0 = blockIdx.y * 128;
    const int tid = threadIdx.x;
    const int wave = tid >> 6, lane = tid & 63;
    const int quad = lane >> 4, l15 = lane & 15;
    const int wm = (wave >> 1) * 64, wn = (wave & 1) * 64;

    __shared__ unsigned short A_s[128][40];
    __shared__ unsigned short B_s[128][40];

    const size_t aBase = (size_t)bz * sAb;
    const size_t bBase = (size_t)bz * sBb;

    f32x4 acc[4][4];
#pragma unroll
    for (int i = 0; i < 4; ++i)
#pragma unroll
        for (int j = 0; j < 4; ++j) acc[i][j] = (f32x4){0.f, 0.f, 0.f, 0.f};

    for (int k0 = 0; k0 < K; k0 += 32) {
#pragma unroll
        for (int g = 0; g < 4; ++g) {
            int c = tid + g * 256;
            int m = c >> 3, kc = (c & 7) * 4;
            float4 f = ld4(A, aBase + (size_t)(m0 + m) * K + k0 + kc, fA);
            *(ushort4*)&A_s[m][kc] = cvt4(f);
        }
        if (!bTrans) {
#pragma unroll
            for (int g = 0; g < 4; ++g) {
                int c = tid + g * 256;
                int n = c >> 3, kc = (c & 7) * 4;
                float4 f = ld4(Bsrc, bBase + (size_t)(n0 + n) * ldB + k0 + kc, fB);
                *(ushort4*)&B_s[n][kc] = cvt4(f);
            }
        } else {
#pragma unroll
            for (int g = 0; g < 4; ++g) {
                int c = tid + g * 256;
                int k = c >> 5, nc = (c & 31) * 4;
                float4 f = ld4(Bsrc, bBase + (size_t)(k0 + k) * ldB + n0 + nc, fB);
                ushort4 u = cvt4(f);
                B_s[nc + 0][k] = u.x;
                B_s[nc + 1][k] = u.y;
                B_s[nc + 2][k] = u.z;
                B_s[nc + 3][k] = u.w;
            }
        }
        __syncthreads();

        bf16x8 a[4], bb[4];
#pragma unroll
        for (int i = 0; i < 4; ++i)
            a[i] = *(const bf16x8*)&A_s[wm + i * 16 + l15][quad * 8];
#pragma unroll
        for (int j = 0; j < 4; ++j)
            bb[j] = *(const bf16x8*)&B_s[wn + j * 16 + l15][quad * 8];
#pragma unroll
        for (int i = 0; i < 4; ++i)
#pragma unroll
            for (int j = 0; j < 4; ++j)
                acc[i][j] = __builtin_amdgcn_mfma_f32_16x16x32_bf16(a[i], bb[j], acc[i][j], 0, 0, 0);
        __syncthreads();
    }

    const size_t cb = (size_t)bz * sCb;
#pragma unroll
    for (int i = 0; i < 4; ++i) {
#pragma unroll
        for (int j = 0; j < 4; ++j) {
            int n = n0 + wn + j * 16 + l15;
#pragma unroll
            for (int r = 0; r < 4; ++r) {
                int m = m0 + wm + i * 16 + quad * 4 + r;
                float v = acc[i][j][r];
                if (addm) {
                    size_t ai = (size_t)bz * sAddb +
                                (addT ? ((size_t)n * M + m) : ((size_t)m * N + n));
                    v += ldm(addm, ai, fAdd);
                }
                if (bias) v += ldm(bias, (size_t)n, fBias);
                size_t ci = cb + (size_t)m * N + n;
                if (c_is_bf16) ((bf16*)C)[ci] = __float2bfloat16(v);
                else           ((float*)C)[ci] = v;
            }
        }
    }
}

// ---------------------------------------------------------------------------
// MFMA banded flash attention with fused rel-shift (unchanged — passing).
// ---------------------------------------------------------------------------
__global__ __launch_bounds__(256)
void attn_mfma(const bf16* __restrict__ wh,  // [B][3072][Q]
               const bf16* __restrict__ rhk, // [1024][Q]
               const void* __restrict__ rwb, // [1024] raw
               const void* __restrict__ rrb, // [1024] raw
               bf16* __restrict__ av_out,    // [B][Q][1024]
               const int* __restrict__ flag)
{
    const int fl = *flag;
    const int it = blockIdx.x, h = blockIdx.y, b = blockIdx.z;
    const int i0 = it * 64;
    const int tid = threadIdx.x;
    const int wave = tid >> 6, lane = tid & 63;
    const int quad = lane >> 4, l15 = lane & 15;
    const int hw = h * 64;

    __shared__ __align__(16) unsigned short sm[32256]; // 64,512 B
    unsigned short* Qrw = sm;          // [64][72]
    unsigned short* Qrr = sm + 4608;   // [64][72]
    unsigned short* Kt  = sm + 9216;   // [64][72]
    unsigned short* Vs  = sm + 13824;  // [64][72]
    unsigned short* Ps  = sm + 18432;  // [64][72]
    unsigned short* Rt  = sm + 23040;  // [128][72]
    unsigned short* Gs  = sm + 23040;  // [64][136] overlay

    const bf16* whb = wh + (size_t)b * QKV3 * QLEN;
    const int d_t = tid & 63;

    {
        float brw = ldm(rwb, hw + d_t, fl);
        float brr = ldm(rrb, hw + d_t, fl);
        const bf16* qrow = whb + (size_t)(hw + d_t) * QLEN + i0;
#pragma unroll
        for (int g = 0; g < 2; ++g) {
            int i8 = (g * 4 + wave) * 8;
            unsigned short u8[8];
            *(uint4*)u8 = *(const uint4*)(qrow + i8);
#pragma unroll
            for (int u = 0; u < 8; ++u) {
                float q = bits2f(u8[u]);
                Qrw[(i8 + u) * 72 + d_t] = f2bs(q + brw);
                Qrr[(i8 + u) * 72 + d_t] = f2bs(q + brr);
            }
        }
    }
    __syncthreads();

    const int qrow_off = (wave * 16 + l15) * 72 + quad * 8;
    bf16x8 qw0 = *(const bf16x8*)&Qrw[qrow_off];
    bf16x8 qw1 = *(const bf16x8*)&Qrw[qrow_off + 32];
    bf16x8 qr0 = *(const bf16x8*)&Qrr[qrow_off];
    bf16x8 qr1 = *(const bf16x8*)&Qrr[qrow_off + 32];

    float m_r[4], l_r[4];
    f32x4 o_acc[4];
#pragma unroll
    for (int r = 0; r < 4; ++r) { m_r[r] = -INFINITY; l_r[r] = 0.f; }
#pragma unroll
    for (int dj = 0; dj < 4; ++dj) o_acc[dj] = (f32x4){0.f, 0.f, 0.f, 0.f};

    int lo = i0 - (LOCAL_SIZE - 1);
    if (lo < 0) lo = 0;

    for (int jt = lo >> 6; jt <= it; ++jt) {
        const int j0 = jt * 64;
        __syncthreads();

        {
            const bf16* krow = whb + (size_t)(1024 + hw + d_t) * QLEN + j0;
#pragma unroll
            for (int g = 0; g < 2; ++g) {
                int j8 = (g * 4 + wave) * 8;
                unsigned short u8[8];
                *(uint4*)u8 = *(const uint4*)(krow + j8);
#pragma unroll
                for (int u = 0; u < 8; ++u) Kt[(j8 + u) * 72 + d_t] = u8[u];
            }
        }
#pragma unroll
        for (int g = 0; g < 2; ++g) {
            int c = g * 256 + tid;
            int d = c >> 3, j8 = (c & 7) * 8;
            *(uint4*)&Vs[d * 72 + j8] =
                *(const uint4*)(whb + (size_t)(2048 + hw + d) * QLEN + j0 + j8);
        }
        {
            const int pbase = j0 - i0 + QLEN - 64;
            const bf16* rrow = rhk + (size_t)(hw + d_t) * QLEN;
#pragma unroll
            for (int g = 0; g < 4; ++g) {
                int t8 = (g * 4 + wave) * 8;
                int p = pbase + t8;
                unsigned short u8[8];
                if (p >= 0 && p + 7 < QLEN) {
                    *(uint4*)u8 = *(const uint4*)(rrow + p);
                } else {
#pragma unroll
                    for (int u = 0; u < 8; ++u) {
                        int pp = p + u;
                        u8[u] = (pp >= 0 && pp < QLEN) ? *(const unsigned short*)(rrow + pp) : 0;
                    }
                }
#pragma unroll
                for (int u = 0; u < 8; ++u) Rt[(t8 + u) * 72 + d_t] = u8[u];
            }
        }
        __syncthreads();

        f32x4 s_acc[4];
#pragma unroll
        for (int nj = 0; nj < 4; ++nj) {
            s_acc[nj] = (f32x4){0.f, 0.f, 0.f, 0.f};
            int ko = (nj * 16 + l15) * 72 + quad * 8;
            bf16x8 b0 = *(const bf16x8*)&Kt[ko];
            bf16x8 b1 = *(const bf16x8*)&Kt[ko + 32];
            s_acc[nj] = __builtin_amdgcn_mfma_f32_16x16x32_bf16(qw0, b0, s_acc[nj], 0, 0, 0);
            s_acc[nj] = __builtin_amdgcn_mfma_f32_16x16x32_bf16(qw1, b1, s_acc[nj], 0, 0, 0);
        }
        f32x4 g_acc[8];
#pragma unroll
        for (int nt = 0; nt < 8; ++nt) {
            g_acc[nt] = (f32x4){0.f, 0.f, 0.f, 0.f};
            int ro = (nt * 16 + l15) * 72 + quad * 8;
            bf16x8 b0 = *(const bf16x8*)&Rt[ro];
            bf16x8 b1 = *(const bf16x8*)&Rt[ro + 32];
            g_acc[nt] = __builtin_amdgcn_mfma_f32_16x16x32_bf16(qr0, b0, g_acc[nt], 0, 0, 0);
            g_acc[nt] = __builtin_amdgcn_mfma_f32_16x16x32_bf16(qr1, b1, g_acc[nt], 0, 0, 0);
        }
        __syncthreads();

#pragma unroll
        for (int nt = 0; nt < 8; ++nt)
#pragma unroll
            for (int r = 0; r < 4; ++r)
                Gs[(wave * 16 + quad * 4 + r) * 136 + nt * 16 + l15] = f2bs(g_acc[nt][r]);

        float sv[4][4];
#pragma unroll
        for (int nj = 0; nj < 4; ++nj) {
#pragma unroll
            for (int r = 0; r < 4; ++r) {
                int i_loc = wave * 16 + quad * 4 + r;
                int j_loc = nj * 16 + l15;
                int t = j_loc - i_loc + 63;
                float bd = bits2f(Gs[i_loc * 136 + t]);
                int diff = (i0 + i_loc) - (j0 + j_loc);
                sv[nj][r] = (diff < 0 || diff >= LOCAL_SIZE)
                                ? -INFINITY
                                : (s_acc[nj][r] + bd) * 0.125f;
            }
        }

        float mnew[4], alpha[4];
#pragma unroll
        for (int r = 0; r < 4; ++r) {
            float tm = fmaxf(fmaxf(sv[0][r], sv[1][r]), fmaxf(sv[2][r], sv[3][r]));
            tm = fmaxf(tm, __shfl_xor(tm, 1));
            tm = fmaxf(tm, __shfl_xor(tm, 2));
            tm = fmaxf(tm, __shfl_xor(tm, 4));
            tm = fmaxf(tm, __shfl_xor(tm, 8));
            mnew[r] = fmaxf(m_r[r], tm);
            alpha[r] = (m_r[r] == -INFINITY) ? 0.f : __expf(m_r[r] - mnew[r]);
        }
#pragma unroll
        for (int r = 0; r < 4; ++r) {
            float rs = 0.f;
#pragma unroll
            for (int nj = 0; nj < 4; ++nj) {
                float p = (mnew[r] == -INFINITY) ? 0.f : __expf(sv[nj][r] - mnew[r]);
                Ps[(wave * 16 + quad * 4 + r) * 72 + nj * 16 + l15] = f2bs(p);
                rs += p;
            }
            rs += __shfl_xor(rs, 1);
            rs += __shfl_xor(rs, 2);
            rs += __shfl_xor(rs, 4);
            rs += __shfl_xor(rs, 8);
            l_r[r] = l_r[r] * alpha[r] + rs;
            m_r[r] = mnew[r];
        }
#pragma unroll
        for (int dj = 0; dj < 4; ++dj)
#pragma unroll
            for (int r = 0; r < 4; ++r) o_acc[dj][r] *= alpha[r];

        {
            int po = (wave * 16 + l15) * 72 + quad * 8;
            bf16x8 pa0 = *(const bf16x8*)&Ps[po];
            bf16x8 pa1 = *(const bf16x8*)&Ps[po + 32];
#pragma unroll
            for (int dj = 0; dj < 4; ++dj) {
                int vo = (dj * 16 + l15) * 72 + quad * 8;
                bf16x8 b0 = *(const bf16x8*)&Vs[vo];
                bf16x8 b1 = *(const bf16x8*)&Vs[vo + 32];
                o_acc[dj] = __builtin_amdgcn_mfma_f32_16x16x32_bf16(pa0, b0, o_acc[dj], 0, 0, 0);
                o_acc[dj] = __builtin_amdgcn_mfma_f32_16x16x32_bf16(pa1, b1, o_acc[dj], 0, 0, 0);
            }
        }
    }

#pragma unroll
    for (int r = 0; r < 4; ++r) {
        float inv = 1.f / l_r[r];
        int q = i0 + wave * 16 + quad * 4 + r;
        bf16* orow = av_out + ((size_t)b * QLEN + q) * D_MODEL + hw;
#pragma unroll
        for (int dj = 0; dj < 4; ++dj)
            orow[dj * 16 + l15] = __float2bfloat16(o_acc[dj][r] * inv);
    }
}

// ---------------------------------------------------------------------------
// Row LayerNorm in place (unchanged).
// ---------------------------------------------------------------------------
__global__ __launch_bounds__(256)
void ln_kernel(float* __restrict__ yt)
{
    const int b = blockIdx.y, q = blockIdx.x;
    float* row = yt + ((size_t)b * QLEN + q) * D_MODEL;
    const int t = threadIdx.x;
    float4 v = ((float4*)row)[t];
    float s  = v.x + v.y + v.z + v.w;
    float ss = v.x * v.x + v.y * v.y + v.z * v.z + v.w * v.w;
#pragma unroll
    for (int off = 32; off; off >>= 1) {
        s  += __shfl_down(s, off);
        ss += __shfl_down(ss, off);
    }
    __shared__ float sw[4], ssw[4];
    const int w = t >> 6;
    if ((t & 63) == 0) { sw[w] = s; ssw[w] = ss; }
    __syncthreads();
    float S  = sw[0] + sw[1] + sw[2] + sw[3];
    float SS = ssw[0] + ssw[1] + ssw[2] + ssw[3];
    float mu  = S / D_MODEL;
    float var = SS / D_MODEL - mu * mu;
    float rs  = rsqrtf(var + 1e-5f);
    v.x = (v.x - mu) * rs; v.y = (v.y - mu) * rs;
    v.z = (v.z - mu) * rs; v.w = (v.w - mu) * rs;
    ((float4*)row)[t] = v;
}

// ---------------------------------------------------------------------------
// Transpose y_t[b][q][o] fp32 -> out[b][o][q] (dtype per flag). Unchanged.
// ---------------------------------------------------------------------------
__global__ __launch_bounds__(256)
void transpose_out(const float* __restrict__ yt, void* __restrict__ out,
                   const int* __restrict__ flag)
{
    const int fl = *flag;
    const int b  = blockIdx.z;
    const int q0 = blockIdx.x * 32;
    const int o0 = blockIdx.y * 32;
    const int tx = threadIdx.x & 31, ty = threadIdx.x >> 5;
    __shared__ float T[32][33];
#pragma unroll
    for (int r = 0; r < 4; ++r) {
        int q = q0 + ty + r * 8;
        T[ty + r * 8][tx] = yt[((size_t)b * QLEN + q) * D_MODEL + o0 + tx];
    }
    __syncthreads();
#pragma unroll
    for (int r = 0; r < 4; ++r) {
        int o = o0 + ty + r * 8;
        size_t oi = ((size_t)b * D_MODEL + o) * QLEN + q0 + tx;
        float v = T[tx][ty + r * 8];
        if (fl) ((float*)out)[oi] = v;
        else    ((bf16*)out)[oi] = __float2bfloat16(v);
    }
}

// ---------------------------------------------------------------------------
extern "C" void kernel_launch(void* const* d_in, const int* in_sizes, int n_in,
                              void* d_out, int out_size, void* d_ws, size_t ws_size,
                              hipStream_t stream)
{
    const void* z1ss = d_in[0];
    const void* pos  = d_in[1];
    const void* u1ss = d_in[2];
    const void* Wqkv = d_in[3];
    const void* Wr   = d_in[4];
    const void* rwb  = d_in[5];
    const void* rrb  = d_in[6];
    const void* Wo   = d_in[7];
    const void* bo   = d_in[8];

    const size_t whE  = (size_t)BSZ * QKV3 * QLEN;     // 12,582,912
    const size_t rhkE = (size_t)D_MODEL * QLEN;        //  2,097,152
    const size_t avE  = (size_t)BSZ * QLEN * D_MODEL;  //  4,194,304
    const size_t ztE  = avE;

    char* ws = (char*)d_ws;
    bf16* wh   = (bf16*)ws;
    bf16* rhk  = wh + whE;
    bf16* avec = rhk + rhkE;
    bf16* post = avec; // overlay: post dead before attn writes avec
    size_t baseB = (whE + rhkE + avE) * sizeof(bf16);  // 37,748,736
    const bool big = ws_size >= baseB + ztE * sizeof(bf16) + 16;
    bf16* zt = (bf16*)(ws + baseB);
    int* flag = (int*)(ws + baseB + (big ? ztE * sizeof(bf16) : 0));
    float* yt = (float*)ws; // overlays wh (dead after attn)

    detect_kernel<<<1, 64, 0, stream>>>((const unsigned short*)Wqkv, flag);

    if (big) {
        // 0. pre-transpose: zt[b][q][d] = z1ss^T (bf16), post[q][d] = pos^T (bf16)
        transpose_cvt<<<dim3(QLEN / 32, D_MODEL / 32, BSZ), 256, 0, stream>>>(
            z1ss, zt, D_MODEL, QLEN, (size_t)D_MODEL * QLEN, (size_t)QLEN * D_MODEL, flag);
        transpose_cvt<<<dim3(QLEN / 32, D_MODEL / 32, 1), 256, 0, stream>>>(
            pos, post, D_MODEL, QLEN, 0, 0, flag);

        // 1. wh[b][o][q] = Wqkv(o,:) . zt[b](q,:) + u1ss
        gemm_bf16<<<dim3(2048 / 128, 3072 / 128, BSZ), 256, 0, stream>>>(
            Wqkv, 2, 0,
            zt, 0, (size_t)QLEN * D_MODEL,
            wh, 1, (size_t)QKV3 * QLEN,
            u1ss, 2, (size_t)QKV3 * QLEN,
            nullptr, 0,
            QKV3, QLEN, D_MODEL, flag);

        // 2. rhk[o][q] = Wr(o,:) . post(q,:)
        gemm_bf16<<<dim3(2048 / 128, 1024 / 128, 1), 256, 0, stream>>>(
            Wr, 2, 0,
            post, 0, 0,
            rhk, 1, 0,
            nullptr, 0, 0,
            nullptr, 0,
            D_MODEL, QLEN, D_MODEL, flag);

        // 3. MFMA banded flash attention -> avec_t[b][q][1024] (overwrites post)
        attn_mfma<<<dim3(QLEN / 64, N_HEAD, BSZ), 256, 0, stream>>>(
            wh, rhk, rwb, rrb, avec, flag);

        // 4. y_t[b][q][o] = avec_t[b](q,:) . Wo(o,:) + bo[o] + zt[b][q][o]
        gemm_bf16<<<dim3(1024 / 128, 2048 / 128, BSZ), 256, 0, stream>>>(
            avec, 0, (size_t)QLEN * D_MODEL,
            Wo, 2, 0,
            yt, 0, (size_t)QLEN * D_MODEL,
            zt, 0, (size_t)QLEN * D_MODEL,
            bo, 2,
            QLEN, D_MODEL, D_MODEL, flag);
    } else {
        // fallback: proven round-4 path (in-GEMM transpose)
        gemm_tn<<<dim3(2048 / 128, 3072 / 128, BSZ), 256, 0, stream>>>(
            Wqkv, 2, 0,
            z1ss, 2, 1, QLEN, (size_t)D_MODEL * QLEN,
            wh, 1, (size_t)QKV3 * QLEN,
            u1ss, 2, 0, (size_t)QKV3 * QLEN,
            nullptr, 0,
            QKV3, QLEN, D_MODEL, flag);
        gemm_tn<<<dim3(2048 / 128, 1024 / 128, 1), 256, 0, stream>>>(
            Wr, 2, 0,
            pos, 2, 1, QLEN, 0,
            rhk, 1, 0,
            nullptr, 0, 0, 0,
            nullptr, 0,
            D_MODEL, QLEN, D_MODEL, flag);
        attn_mfma<<<dim3(QLEN / 64, N_HEAD, BSZ), 256, 0, stream>>>(
            wh, rhk, rwb, rrb, avec, flag);
        gemm_tn<<<dim3(1024 / 128, 2048 / 128, BSZ), 256, 0, stream>>>(
            avec, 0, (size_t)QLEN * D_MODEL,
            Wo, 2, 0, D_MODEL, 0,
            yt, 0, (size_t)QLEN * D_MODEL,
            z1ss, 2, 1, (size_t)D_MODEL * QLEN,
            bo, 2,
            QLEN, D_MODEL, D_MODEL, flag);
    }

    // 5. LN in place on y_t rows
    ln_kernel<<<dim3(QLEN, BSZ), 256, 0, stream>>>(yt);

    // 6. transpose to out[b][o][q]
    transpose_out<<<dim3(QLEN / 32, D_MODEL / 32, BSZ), 256, 0, stream>>>(yt, d_out, flag);
}